// Round 11
// baseline (743.801 us; speedup 1.0000x reference)
//
#include <hip/hip_runtime.h>
#include <cstddef>
#include <cstdint>

#define N_NODES 50000
#define N_EDGES 800000
#define NP 50048   // 391 * 128, padded row count
static constexpr float BN_EPS = 1e-5f;
static constexpr int NREP = 32;  // replicated stat accumulators

typedef unsigned short u16;
typedef short bf16x8 __attribute__((ext_vector_type(8)));
typedef float f32x4 __attribute__((ext_vector_type(4)));

// ---------------- helpers ----------------
__device__ inline u16 f2bf(float f) {
    union { float f; unsigned u; } v; v.f = f;
    unsigned r = v.u + 0x7fffu + ((v.u >> 16) & 1u);
    return (u16)(r >> 16);
}
__device__ inline unsigned pack2(float a, float b) {
    return (unsigned)f2bf(a) | ((unsigned)f2bf(b) << 16);
}
__device__ inline void addbf2(unsigned u, float& lo, float& hi) {
    union { unsigned u; float f; } t;
    t.u = u << 16; lo += t.f;
    t.u = u & 0xFFFF0000u; hi += t.f;
}
__device__ inline void bf2(unsigned u, float& lo, float& hi) {
    union { unsigned u; float f; } t;
    t.u = u << 16; lo = t.f;
    t.u = u & 0xFFFF0000u; hi = t.f;
}
__device__ inline uint4 bnrelu_pack(uint4 v, float4 sc0, float4 sc1, float4 sh0, float4 sh1) {
    float x0, x1, x2, x3, x4, x5, x6, x7;
    bf2(v.x, x0, x1); bf2(v.y, x2, x3); bf2(v.z, x4, x5); bf2(v.w, x6, x7);
    x0 = fmaxf(fmaf(x0, sc0.x, sh0.x), 0.f); x1 = fmaxf(fmaf(x1, sc0.y, sh0.y), 0.f);
    x2 = fmaxf(fmaf(x2, sc0.z, sh0.z), 0.f); x3 = fmaxf(fmaf(x3, sc0.w, sh0.w), 0.f);
    x4 = fmaxf(fmaf(x4, sc1.x, sh1.x), 0.f); x5 = fmaxf(fmaf(x5, sc1.y, sh1.y), 0.f);
    x6 = fmaxf(fmaf(x6, sc1.z, sh1.z), 0.f); x7 = fmaxf(fmaf(x7, sc1.w, sh1.w), 0.f);
    uint4 u;
    u.x = pack2(x0, x1); u.y = pack2(x2, x3);
    u.z = pack2(x4, x5); u.w = pack2(x6, x7);
    return u;
}

// ---------------- prologue: convert x, zero deg/stats, build weights ----------------
__global__ __launch_bounds__(256) void prologue(const float* __restrict__ in,
                                                u16* __restrict__ out, int n8,
                                                int* __restrict__ dz, int ndz4,
                                                float* __restrict__ sz, int nsz4,
                                                const float* __restrict__ w1l, const float* __restrict__ w1r,
                                                const float* __restrict__ w2l, const float* __restrict__ w2r,
                                                const float* __restrict__ w3l, const float* __restrict__ w3r,
                                                const float* __restrict__ b2l, const float* __restrict__ b3l,
                                                u16* __restrict__ wt1, u16* __restrict__ wt2,
                                                u16* __restrict__ wt3,
                                                float* __restrict__ bias2, float* __restrict__ bias3) {
    const int tid = blockIdx.x * 256 + threadIdx.x;
    const int stride = gridDim.x * 256;
    int4* d4 = (int4*)dz;
    for (int i = tid; i < ndz4; i += stride) d4[i] = make_int4(0, 0, 0, 0);
    float4* z4 = (float4*)sz;
    for (int i = tid; i < nsz4; i += stride) z4[i] = make_float4(0.f, 0.f, 0.f, 0.f);
    const float4* in4 = (const float4*)in;
    uint4* out4 = (uint4*)out;
    for (int i = tid; i < n8; i += stride) {
        float4 a = in4[2 * i], b = in4[2 * i + 1];
        uint4 u;
        u.x = pack2(a.x, a.y); u.y = pack2(a.z, a.w);
        u.z = pack2(b.x, b.y); u.w = pack2(b.z, b.w);
        out4[i] = u;
    }
    for (int i = tid; i < 213376; i += stride) {
        int idx = i;
        if (idx < 131072) {  // wt1[n][k]: K=512 concat-K
            int n = idx >> 9, k = idx & 511;
            float v = (k < 256) ? w1l[(size_t)k * 256 + n] : w1r[(size_t)(k - 256) * 256 + n];
            wt1[idx] = f2bf(v); continue;
        }
        idx -= 131072;
        if (idx < 65536) {   // wt2[n][k]: concat-N, D=128
            int n = idx >> 8, k = idx & 255;
            float v = (n < 128) ? w2l[(size_t)k * 128 + n] : w2r[(size_t)k * 128 + (n - 128)];
            wt2[idx] = f2bf(v); continue;
        }
        idx -= 65536;
        if (idx < 16384) {   // wt3[n][k]: concat-N, D=64
            int n = idx >> 7, k = idx & 127;
            float v = (n < 64) ? w3l[(size_t)k * 64 + n] : w3r[(size_t)k * 64 + (n - 64)];
            wt3[idx] = f2bf(v); continue;
        }
        idx -= 16384;
        if (idx < 256) { bias2[idx] = (idx < 128) ? 0.f : b2l[idx - 128]; continue; }
        idx -= 256;
        if (idx < 128) { bias3[idx] = (idx < 64) ? 0.f : b3l[idx - 64]; continue; }
    }
}

// ---------------- CSR build ----------------
__global__ void deg_count(const int* __restrict__ dst, int* __restrict__ deg, int E) {
    int i = blockIdx.x * blockDim.x + threadIdx.x;
    if (i < E) atomicAdd(&deg[dst[i]], 1);
}

__global__ __launch_bounds__(256) void scan_phase1(const int* __restrict__ deg,
                                                   int* __restrict__ rowptr,
                                                   int* __restrict__ blocksum, int n) {
    __shared__ int s[256];
    const int t = threadIdx.x;
    const int i = blockIdx.x * 256 + t;
    int d = (i < n) ? deg[i] : 0;
    s[t] = d;
    __syncthreads();
    for (int off = 1; off < 256; off <<= 1) {
        int v = (t >= off) ? s[t - off] : 0;
        __syncthreads();
        s[t] += v;
        __syncthreads();
    }
    if (i < n) rowptr[i] = s[t] - d;
    if (t == 255) blocksum[blockIdx.x] = s[t];
}

__global__ __launch_bounds__(256) void scan_phase2(int* __restrict__ blocksum,
                                                   int* __restrict__ rowptr, int nb, int n) {
    __shared__ int s[256];
    const int t = threadIdx.x;
    int d = (t < nb) ? blocksum[t] : 0;
    s[t] = d;
    __syncthreads();
    for (int off = 1; off < 256; off <<= 1) {
        int v = (t >= off) ? s[t - off] : 0;
        __syncthreads();
        s[t] += v;
        __syncthreads();
    }
    if (t < nb) blocksum[t] = s[t] - d;
    if (t == 255) rowptr[n] = s[t];
}

__global__ __launch_bounds__(256) void scan_phase3(int* __restrict__ rowptr,
                                                   const int* __restrict__ blocksum,
                                                   const int* __restrict__ deg,
                                                   float* __restrict__ inv,
                                                   int* __restrict__ cursor, int n) {
    int i = blockIdx.x * 256 + threadIdx.x;
    if (i >= n) return;
    rowptr[i] += blocksum[i >> 8];
    inv[i] = 1.0f / fmaxf((float)deg[i], 1.0f);
    cursor[i] = 0;
}

__global__ void csr_fill(const int* __restrict__ src, const int* __restrict__ dst,
                         const int* __restrict__ rowptr, int* __restrict__ cursor,
                         int* __restrict__ csr, int E) {
    int e = blockIdx.x * blockDim.x + threadIdx.x;
    if (e >= E) return;
    int d = dst[e];
    int p = atomicAdd(&cursor[d], 1);
    csr[rowptr[d] + p] = src[e];
}

// ---------------- gather-mean (layer 1): index-prefetch pipeline ----------------
template <int KH>
__global__ __launch_bounds__(256) void gather_mean_bf16(const u16* __restrict__ F,
                                                        const int* __restrict__ rowptr,
                                                        const int* __restrict__ csr,
                                                        const float* __restrict__ inv,
                                                        u16* __restrict__ Sout, int N) {
    constexpr int CG = KH / 8;
    constexpr int NPB = 256 / CG;
    const int c = threadIdx.x % CG;
    const int node = blockIdx.x * NPB + threadIdx.x / CG;
    if (node >= N) return;
    const uint4* F4 = (const uint4*)F;
    float a0 = 0, a1 = 0, a2 = 0, a3 = 0, a4 = 0, a5 = 0, a6 = 0, a7 = 0;
    const int beg = rowptr[node], end = rowptr[node + 1];
    int k = beg;
    if (end - beg >= 4) {
        int i0 = csr[k], i1 = csr[k + 1], i2 = csr[k + 2], i3 = csr[k + 3];
        k += 4;
        for (; k + 3 < end; k += 4) {
            uint4 v0 = F4[(size_t)i0 * CG + c];
            uint4 v1 = F4[(size_t)i1 * CG + c];
            uint4 v2 = F4[(size_t)i2 * CG + c];
            uint4 v3 = F4[(size_t)i3 * CG + c];
            i0 = csr[k]; i1 = csr[k + 1]; i2 = csr[k + 2]; i3 = csr[k + 3];
            addbf2(v0.x, a0, a1); addbf2(v0.y, a2, a3); addbf2(v0.z, a4, a5); addbf2(v0.w, a6, a7);
            addbf2(v1.x, a0, a1); addbf2(v1.y, a2, a3); addbf2(v1.z, a4, a5); addbf2(v1.w, a6, a7);
            addbf2(v2.x, a0, a1); addbf2(v2.y, a2, a3); addbf2(v2.z, a4, a5); addbf2(v2.w, a6, a7);
            addbf2(v3.x, a0, a1); addbf2(v3.y, a2, a3); addbf2(v3.z, a4, a5); addbf2(v3.w, a6, a7);
        }
        uint4 v0 = F4[(size_t)i0 * CG + c];
        uint4 v1 = F4[(size_t)i1 * CG + c];
        uint4 v2 = F4[(size_t)i2 * CG + c];
        uint4 v3 = F4[(size_t)i3 * CG + c];
        addbf2(v0.x, a0, a1); addbf2(v0.y, a2, a3); addbf2(v0.z, a4, a5); addbf2(v0.w, a6, a7);
        addbf2(v1.x, a0, a1); addbf2(v1.y, a2, a3); addbf2(v1.z, a4, a5); addbf2(v1.w, a6, a7);
        addbf2(v2.x, a0, a1); addbf2(v2.y, a2, a3); addbf2(v2.z, a4, a5); addbf2(v2.w, a6, a7);
        addbf2(v3.x, a0, a1); addbf2(v3.y, a2, a3); addbf2(v3.z, a4, a5); addbf2(v3.w, a6, a7);
    }
    for (; k < end; ++k) {
        uint4 v0 = F4[(size_t)csr[k] * CG + c];
        addbf2(v0.x, a0, a1); addbf2(v0.y, a2, a3); addbf2(v0.z, a4, a5); addbf2(v0.w, a6, a7);
    }
    const float w = inv[node];
    uint4 u;
    u.x = pack2(a0 * w, a1 * w); u.y = pack2(a2 * w, a3 * w);
    u.z = pack2(a4 * w, a5 * w); u.w = pack2(a6 * w, a7 * w);
    ((uint4*)Sout)[(size_t)node * CG + c] = u;
}

// ---------------- gather-add + fused BN stats (shfl-reduce) + ticket finalize ----------------
template <int D>
__global__ __launch_bounds__(256) void gather_add_stats2(const u16* __restrict__ PQ,
                                                         const int* __restrict__ rowptr,
                                                         const int* __restrict__ csr,
                                                         const float* __restrict__ inv,
                                                         u16* __restrict__ Hpre,
                                                         float* __restrict__ repS,
                                                         float* __restrict__ repQ,
                                                         const float* __restrict__ g,
                                                         const float* __restrict__ beta,
                                                         float* __restrict__ scale,
                                                         float* __restrict__ shift,
                                                         int* __restrict__ ticket,
                                                         int nblocks, int N) {
    constexpr int CG = D / 8;
    constexpr int NPB = 256 / CG;
    constexpr int RS4 = D / 4;
    const int t = threadIdx.x;
    const int c = t % CG;
    const int node = blockIdx.x * NPB + t / CG;
    float y[8] = {};
    if (node < N) {
        const uint4* PQ4 = (const uint4*)PQ;
        float a0 = 0, a1 = 0, a2 = 0, a3 = 0, a4 = 0, a5 = 0, a6 = 0, a7 = 0;
        const int beg = rowptr[node], end = rowptr[node + 1];
        int k = beg;
        if (end - beg >= 4) {
            int i0 = csr[k], i1 = csr[k + 1], i2 = csr[k + 2], i3 = csr[k + 3];
            k += 4;
            for (; k + 3 < end; k += 4) {
                uint4 v0 = PQ4[(size_t)i0 * RS4 + c];
                uint4 v1 = PQ4[(size_t)i1 * RS4 + c];
                uint4 v2 = PQ4[(size_t)i2 * RS4 + c];
                uint4 v3 = PQ4[(size_t)i3 * RS4 + c];
                i0 = csr[k]; i1 = csr[k + 1]; i2 = csr[k + 2]; i3 = csr[k + 3];
                addbf2(v0.x, a0, a1); addbf2(v0.y, a2, a3); addbf2(v0.z, a4, a5); addbf2(v0.w, a6, a7);
                addbf2(v1.x, a0, a1); addbf2(v1.y, a2, a3); addbf2(v1.z, a4, a5); addbf2(v1.w, a6, a7);
                addbf2(v2.x, a0, a1); addbf2(v2.y, a2, a3); addbf2(v2.z, a4, a5); addbf2(v2.w, a6, a7);
                addbf2(v3.x, a0, a1); addbf2(v3.y, a2, a3); addbf2(v3.z, a4, a5); addbf2(v3.w, a6, a7);
            }
            uint4 v0 = PQ4[(size_t)i0 * RS4 + c];
            uint4 v1 = PQ4[(size_t)i1 * RS4 + c];
            uint4 v2 = PQ4[(size_t)i2 * RS4 + c];
            uint4 v3 = PQ4[(size_t)i3 * RS4 + c];
            addbf2(v0.x, a0, a1); addbf2(v0.y, a2, a3); addbf2(v0.z, a4, a5); addbf2(v0.w, a6, a7);
            addbf2(v1.x, a0, a1); addbf2(v1.y, a2, a3); addbf2(v1.z, a4, a5); addbf2(v1.w, a6, a7);
            addbf2(v2.x, a0, a1); addbf2(v2.y, a2, a3); addbf2(v2.z, a4, a5); addbf2(v2.w, a6, a7);
            addbf2(v3.x, a0, a1); addbf2(v3.y, a2, a3); addbf2(v3.z, a4, a5); addbf2(v3.w, a6, a7);
        }
        for (; k < end; ++k) {
            uint4 v0 = PQ4[(size_t)csr[k] * RS4 + c];
            addbf2(v0.x, a0, a1); addbf2(v0.y, a2, a3); addbf2(v0.z, a4, a5); addbf2(v0.w, a6, a7);
        }
        const float w = inv[node];
        uint4 q = PQ4[(size_t)node * RS4 + D / 8 + c];
        float q0, q1, q2, q3, q4, q5, q6, q7;
        bf2(q.x, q0, q1); bf2(q.y, q2, q3); bf2(q.z, q4, q5); bf2(q.w, q6, q7);
        uint4 u;
        u.x = pack2(a0 * w + q0, a1 * w + q1);
        u.y = pack2(a2 * w + q2, a3 * w + q3);
        u.z = pack2(a4 * w + q4, a5 * w + q5);
        u.w = pack2(a6 * w + q6, a7 * w + q7);
        ((uint4*)Hpre)[(size_t)node * (D / 8) + c] = u;
        bf2(u.x, y[0], y[1]); bf2(u.y, y[2], y[3]);
        bf2(u.z, y[4], y[5]); bf2(u.w, y[6], y[7]);
    }
    // stats: shfl-butterfly over node-groups within the wave (lanes with equal c)
    float sq[8];
#pragma unroll
    for (int j = 0; j < 8; ++j) sq[j] = y[j] * y[j];
#pragma unroll
    for (int off = CG; off < 64; off <<= 1) {
#pragma unroll
        for (int j = 0; j < 8; ++j) {
            y[j] += __shfl_xor(y[j], off);
            sq[j] += __shfl_xor(sq[j], off);
        }
    }
    __shared__ float redS[4][D], redQ[4][D];
    const int w = t >> 6;
    if ((t & 63) < CG) {
#pragma unroll
        for (int j = 0; j < 8; ++j) {
            redS[w][c * 8 + j] = y[j];
            redQ[w][c * 8 + j] = sq[j];
        }
    }
    __syncthreads();
    const int rep = (blockIdx.x & (NREP - 1)) * D;
    if (t < D) {
        float s = redS[0][t] + redS[1][t] + redS[2][t] + redS[3][t];
        float ss = redQ[0][t] + redQ[1][t] + redQ[2][t] + redQ[3][t];
        atomicAdd(&repS[rep + t], s);
        atomicAdd(&repQ[rep + t], ss);
    }
    // last-block finalize
    __threadfence();
    __shared__ int lastflag;
    if (t == 0) lastflag = (atomicAdd(ticket, 1) == nblocks - 1) ? 1 : 0;
    __syncthreads();
    if (lastflag) {
        for (int j = t; j < D; j += 256) {
            float s = 0.f, ss = 0.f;
            for (int r = 0; r < NREP; ++r) {
                s += atomicAdd(&repS[r * D + j], 0.f);
                ss += atomicAdd(&repQ[r * D + j], 0.f);
            }
            float mean = s / N;
            float var = fmaxf(ss / N - mean * mean, 0.f);
            float sc = g[j] * rsqrtf(var + BN_EPS);
            scale[j] = sc;
            shift[j] = beta[j] - mean * sc;
        }
    }
}

// ---------------- MFMA GEMM ----------------
// STATS: fused column sums/sumsq + ticket-finalized BN (scale/shift written by last block).
// BNA: A reg-staged from S with fused relu(a*SC+SH) before swizzled ds_write.
template <int KH, int K, int NOUT, bool STATS, bool BNA>
__global__ __launch_bounds__(256, 1) void sage_gemm(const u16* __restrict__ S,
                                                    const u16* __restrict__ X,
                                                    const u16* __restrict__ WT,
                                                    const float* __restrict__ BL,
                                                    const float* __restrict__ SC,
                                                    const float* __restrict__ SH,
                                                    u16* __restrict__ Hb,
                                                    float* __restrict__ sums,
                                                    float* __restrict__ sumsq,
                                                    const float* __restrict__ g,
                                                    const float* __restrict__ beta,
                                                    float* __restrict__ oscale,
                                                    float* __restrict__ oshift,
                                                    int* __restrict__ ticket,
                                                    int nblocks, int M) {
    constexpr int NK = K / 32;
    constexpr int FN = NOUT / 32;
    constexpr int BUFSZ = 4096 + NOUT * 32;
    __shared__ __align__(16) u16 lds[2][BUFSZ];
    const int t = threadIdx.x;
    const int wid = t >> 6, lane = t & 63;
    const int row0 = blockIdx.x * 128;
    const int wm = wid >> 1, wn = wid & 1;
    const int fr = lane & 15, fc = lane >> 4;
    const int swz8 = (((lane & 3) ^ ((lane >> 3) & 3)) * 8);

    auto stageA_lds = [&](int buf, int ks) {
        const int k0 = ks * 32;
        const u16* srcA;
        int kb;
        if (k0 < KH) { srcA = S; kb = k0; } else { srcA = X; kb = k0 - KH; }
#pragma unroll
        for (int jj = 0; jj < 2; ++jj) {
            int j = wid + jj * 4;
            const u16* gptr = srcA + (size_t)(row0 + j * 16 + (lane >> 2)) * KH + kb + swz8;
            __builtin_amdgcn_global_load_lds(
                (const __attribute__((address_space(1))) void*)gptr,
                (__attribute__((address_space(3))) void*)&lds[buf][j * 512], 16, 0, 0);
        }
    };
    auto stageB = [&](int buf, int ks) {
        const int k0 = ks * 32;
#pragma unroll
        for (int jj = 0; jj < NOUT / 64; ++jj) {
            int j = wid * (NOUT / 64) + jj;
            const u16* gb = WT + (size_t)(j * 16 + (lane >> 2)) * K + k0 + swz8;
            __builtin_amdgcn_global_load_lds(
                (const __attribute__((address_space(1))) void*)gb,
                (__attribute__((address_space(3))) void*)&lds[buf][4096 + j * 512], 16, 0, 0);
        }
    };

    uint4 rA[2];
    auto loadA = [&](int ks) {
        const int k0 = ks * 32;
#pragma unroll
        for (int jj = 0; jj < 2; ++jj) {
            int j = wid + jj * 4;
            rA[jj] = *(const uint4*)(S + (size_t)(row0 + j * 16 + (lane >> 2)) * KH + k0 + swz8);
        }
    };
    auto writeA = [&](int buf, int ks) {
        const int k0 = ks * 32;
        float4 sc0 = *(const float4*)&SC[k0 + swz8];
        float4 sc1 = *(const float4*)&SC[k0 + swz8 + 4];
        float4 sh0 = *(const float4*)&SH[k0 + swz8];
        float4 sh1 = *(const float4*)&SH[k0 + swz8 + 4];
#pragma unroll
        for (int jj = 0; jj < 2; ++jj) {
            int j = wid + jj * 4;
            *(uint4*)&lds[buf][(size_t)j * 512 + lane * 8] = bnrelu_pack(rA[jj], sc0, sc1, sh0, sh1);
        }
    };

    f32x4 acc[4][FN] = {};

    auto compute = [&](int buf) {
        const u16* A = &lds[buf][0];
        const u16* B = &lds[buf][4096];
        const int swr = (fr >> 1) & 3;
        const int kc = (fc ^ swr) * 8;
        bf16x8 a[4], b[FN];
#pragma unroll
        for (int fm = 0; fm < 4; ++fm)
            a[fm] = *(const bf16x8*)&A[(wm * 64 + fm * 16 + fr) * 32 + kc];
#pragma unroll
        for (int fn = 0; fn < FN; ++fn)
            b[fn] = *(const bf16x8*)&B[(wn * (NOUT / 2) + fn * 16 + fr) * 32 + kc];
#pragma unroll
        for (int fm = 0; fm < 4; ++fm)
#pragma unroll
            for (int fn = 0; fn < FN; ++fn)
                acc[fm][fn] = __builtin_amdgcn_mfma_f32_16x16x32_bf16(a[fm], b[fn], acc[fm][fn], 0, 0, 0);
    };

    if constexpr (BNA) {
        static_assert(KH == K, "BNA requires single operand");
        loadA(0);
        writeA(0, 0);
        stageB(0, 0);
        if (NK > 1) loadA(1);
        for (int ks = 0; ks < NK; ++ks) {
            __syncthreads();
            if (ks + 1 < NK) {
                writeA((ks + 1) & 1, ks + 1);
                stageB((ks + 1) & 1, ks + 1);
                if (ks + 2 < NK) loadA(ks + 2);
            }
            compute(ks & 1);
        }
    } else {
        stageA_lds(0, 0);
        stageB(0, 0);
        for (int ks = 0; ks < NK; ++ks) {
            __syncthreads();
            if (ks + 1 < NK) {
                stageA_lds((ks + 1) & 1, ks + 1);
                stageB((ks + 1) & 1, ks + 1);
            }
            compute(ks & 1);
        }
    }

    const int cw = wn * (NOUT / 2);
    float bias[FN], s[FN], ss[FN];
#pragma unroll
    for (int fn = 0; fn < FN; ++fn) {
        bias[fn] = BL[cw + fn * 16 + fr];
        s[fn] = 0.f; ss[fn] = 0.f;
    }
#pragma unroll
    for (int fm = 0; fm < 4; ++fm) {
#pragma unroll
        for (int q = 0; q < 4; ++q) {
            int r = row0 + wm * 64 + fm * 16 + fc * 4 + q;
            if (r < M) {
#pragma unroll
                for (int fn = 0; fn < FN; ++fn) {
                    float h = acc[fm][fn][q] + bias[fn];
                    Hb[(size_t)r * NOUT + cw + fn * 16 + fr] = f2bf(h);
                    if constexpr (STATS) { s[fn] += h; ss[fn] += h * h; }
                }
            }
        }
    }
    if constexpr (STATS) {
#pragma unroll
        for (int fn = 0; fn < FN; ++fn) {
            float sv = s[fn], sq = ss[fn];
            sv += __shfl_xor(sv, 16); sv += __shfl_xor(sv, 32);
            sq += __shfl_xor(sq, 16); sq += __shfl_xor(sq, 32);
            if (fc == 0) {
                atomicAdd(&sums[cw + fn * 16 + fr], sv);
                atomicAdd(&sumsq[cw + fn * 16 + fr], sq);
            }
        }
        // last-block BN finalize
        __threadfence();
        __shared__ int lastflag;
        if (t == 0) lastflag = (atomicAdd(ticket, 1) == nblocks - 1) ? 1 : 0;
        __syncthreads();
        if (lastflag) {
            for (int j = t; j < NOUT; j += 256) {
                float sv = atomicAdd(&sums[j], 0.f);
                float sq = atomicAdd(&sumsq[j], 0.f);
                float mean = sv / M;
                float var = fmaxf(sq / M - mean * mean, 0.f);
                float sc = g[j] * rsqrtf(var + BN_EPS);
                oscale[j] = sc;
                oshift[j] = beta[j] - mean * sc;
            }
        }
    }
}

// ---------------- head with fused BN3+ReLU ----------------
__global__ __launch_bounds__(256) void head_bn(const u16* __restrict__ H3pre,
                                               const float* __restrict__ sc,
                                               const float* __restrict__ sh,
                                               const float* __restrict__ wh,
                                               const float* __restrict__ bh,
                                               float* __restrict__ out, int n) {
    int i = blockIdx.x * blockDim.x + threadIdx.x;
    if (i >= n) return;
    const uint4* h4 = (const uint4*)(H3pre + (size_t)i * 64);
    float acc = bh[0];
#pragma unroll
    for (int c = 0; c < 8; ++c) {
        uint4 v = h4[c];
        float x0, x1, x2, x3, x4, x5, x6, x7;
        bf2(v.x, x0, x1); bf2(v.y, x2, x3); bf2(v.z, x4, x5); bf2(v.w, x6, x7);
        const float* s = sc + c * 8;
        const float* t = sh + c * 8;
        const float* w = wh + c * 8;
        acc += fmaxf(fmaf(x0, s[0], t[0]), 0.f) * w[0];
        acc += fmaxf(fmaf(x1, s[1], t[1]), 0.f) * w[1];
        acc += fmaxf(fmaf(x2, s[2], t[2]), 0.f) * w[2];
        acc += fmaxf(fmaf(x3, s[3], t[3]), 0.f) * w[3];
        acc += fmaxf(fmaf(x4, s[4], t[4]), 0.f) * w[4];
        acc += fmaxf(fmaf(x5, s[5], t[5]), 0.f) * w[5];
        acc += fmaxf(fmaf(x6, s[6], t[6]), 0.f) * w[6];
        acc += fmaxf(fmaf(x7, s[7], t[7]), 0.f) * w[7];
    }
    out[i] = acc;
}

// ---------------- launch ----------------
extern "C" void kernel_launch(void* const* d_in, const int* in_sizes, int n_in,
                              void* d_out, int out_size, void* d_ws, size_t ws_size,
                              hipStream_t stream) {
    const int N = N_NODES, E = N_EDGES;
    const float* x   = (const float*)d_in[0];
    const int*   ei  = (const int*)d_in[1];
    const int*   src = ei;
    const int*   dst = ei + E;
    const float* w1l = (const float*)d_in[2];
    const float* b1l = (const float*)d_in[3];
    const float* w1r = (const float*)d_in[4];
    const float* g1  = (const float*)d_in[5];
    const float* be1 = (const float*)d_in[6];
    const float* w2l = (const float*)d_in[7];
    const float* b2l = (const float*)d_in[8];
    const float* w2r = (const float*)d_in[9];
    const float* g2  = (const float*)d_in[10];
    const float* be2 = (const float*)d_in[11];
    const float* w3l = (const float*)d_in[12];
    const float* b3l = (const float*)d_in[13];
    const float* w3r = (const float*)d_in[14];
    const float* g3  = (const float*)d_in[15];
    const float* be3 = (const float*)d_in[16];
    const float* wh  = (const float*)d_in[17];
    const float* bh  = (const float*)d_in[18];
    float* out = (float*)d_out;

    // ---- workspace layout ----
    char* base = (char*)d_ws;
    size_t off = 0;
    auto alloc = [&](size_t bytes) -> void* {
        void* r = base + off;
        off += (bytes + 255) & ~(size_t)255;
        return r;
    };
    const int NB = (N + 255) / 256;  // 196
    int*   rowptr = (int*)alloc((N + 8) * sizeof(int));
    int*   csr    = (int*)alloc((size_t)E * sizeof(int));
    int*   deg_i  = (int*)alloc(N * sizeof(int));
    int*   cursor = (int*)alloc(N * sizeof(int));
    int*   bsum   = (int*)alloc(256 * sizeof(int));
    float* inv    = (float*)alloc(N * sizeof(float));
    u16*   xb     = (u16*)alloc((size_t)NP * 256 * 2);
    u16*   sB     = (u16*)alloc((size_t)NP * 256 * 2);
    u16*   hpre1  = (u16*)alloc((size_t)NP * 256 * 2);
    u16*   hpre2  = (u16*)alloc((size_t)NP * 256 * 2);   // [P|Q] layer 2
    u16*   h2pre  = (u16*)alloc((size_t)NP * 128 * 2);
    u16*   hpre3  = (u16*)alloc((size_t)NP * 128 * 2);   // [P|Q] layer 3
    u16*   h3pre  = (u16*)alloc((size_t)NP * 64 * 2);
    u16*   wt1    = (u16*)alloc((size_t)131072 * 2);
    u16*   wt2    = (u16*)alloc((size_t)65536 * 2);
    u16*   wt3    = (u16*)alloc((size_t)16384 * 2);
    // stats zeroed prefix: [sums1 256][sumsq1 256][rep2S 32*128][rep2Q 32*128]
    //                      [rep3S 32*64][rep3Q 32*64][tickets 8]
    const int ZFLOATS = 256 + 256 + NREP * 128 * 2 + NREP * 64 * 2 + 8;  // 12808
    float* stats  = (float*)alloc((ZFLOATS + 896) * sizeof(float));
    float* sums1 = stats,       *sumsq1 = stats + 256;
    float* rep2S = stats + 512,             *rep2Q = rep2S + NREP * 128;
    float* rep3S = rep2Q + NREP * 128,      *rep3Q = rep3S + NREP * 64;
    int*   ticket1 = (int*)(rep3Q + NREP * 64);
    int*   ticket2 = ticket1 + 1;
    int*   ticket3 = ticket1 + 2;
    float* post   = stats + ZFLOATS;
    float* scale1 = post,       *shift1 = post + 256;
    float* scale2 = post + 512, *shift2 = post + 640;
    float* scale3 = post + 768, *shift3 = post + 832;
    float* bias2  = (float*)alloc(256 * sizeof(float));
    float* bias3  = (float*)alloc(128 * sizeof(float));

    const int MB = NP / 128;  // 391

    // prologue: convert x, zero deg+stats+tickets, build weights/biases
    prologue<<<2048, 256, 0, stream>>>(x, xb, N * 256 / 8, deg_i, N / 4,
                                       stats, ZFLOATS / 4,
                                       w1l, w1r, w2l, w2r, w3l, w3r, b2l, b3l,
                                       wt1, wt2, wt3, bias2, bias3);

    // CSR build
    deg_count<<<(E + 255) / 256, 256, 0, stream>>>(dst, deg_i, E);
    scan_phase1<<<NB, 256, 0, stream>>>(deg_i, rowptr, bsum, N);
    scan_phase2<<<1, 256, 0, stream>>>(bsum, rowptr, NB, N);
    scan_phase3<<<NB, 256, 0, stream>>>(rowptr, bsum, deg_i, inv, cursor, N);
    csr_fill<<<(E + 255) / 256, 256, 0, stream>>>(src, dst, rowptr, cursor, csr, E);

    // layer 1: agg-first, [S|X] K=512 -> 256, stats + BN1 finalize fused in GEMM
    gather_mean_bf16<256><<<(N * 32 + 255) / 256, 256, 0, stream>>>(xb, rowptr, csr, inv, sB, N);
    sage_gemm<256, 512, 256, true, false><<<MB, 256, 0, stream>>>(
        sB, xb, wt1, b1l, nullptr, nullptr, hpre1, sums1, sumsq1,
        g1, be1, scale1, shift1, ticket1, MB, N);

    // layer 2: transform-first, BN1+ReLU fused into A staging; stats fused in gather
    sage_gemm<256, 256, 256, false, true><<<MB, 256, 0, stream>>>(
        hpre1, hpre1, wt2, bias2, scale1, shift1, hpre2, nullptr, nullptr,
        nullptr, nullptr, nullptr, nullptr, nullptr, 0, N);
    gather_add_stats2<128><<<(N * 16 + 255) / 256, 256, 0, stream>>>(
        hpre2, rowptr, csr, inv, h2pre, rep2S, rep2Q,
        g2, be2, scale2, shift2, ticket2, (N * 16 + 255) / 256, N);

    // layer 3: transform-first, BN2+ReLU fused into A staging; stats fused in gather
    sage_gemm<128, 128, 128, false, true><<<MB, 256, 0, stream>>>(
        h2pre, h2pre, wt3, bias3, scale2, shift2, hpre3, nullptr, nullptr,
        nullptr, nullptr, nullptr, nullptr, nullptr, 0, N);
    gather_add_stats2<64><<<(N * 8 + 255) / 256, 256, 0, stream>>>(
        hpre3, rowptr, csr, inv, h3pre, rep3S, rep3Q,
        g3, be3, scale3, shift3, ticket3, (N * 8 + 255) / 256, N);

    // head with fused BN3+ReLU
    head_bn<<<(N + 255) / 256, 256, 0, stream>>>(h3pre, scale3, shift3, wh, bh, out, N);
}

// Round 12
// 313.289 us; speedup vs baseline: 2.3742x; 2.3742x over previous
//
#include <hip/hip_runtime.h>
#include <cstddef>
#include <cstdint>

#define N_NODES 50000
#define N_EDGES 800000
#define NP 50048   // 391 * 128, padded row count
static constexpr float BN_EPS = 1e-5f;

typedef unsigned short u16;
typedef short bf16x8 __attribute__((ext_vector_type(8)));
typedef float f32x4 __attribute__((ext_vector_type(4)));

// ---------------- helpers ----------------
__device__ inline u16 f2bf(float f) {
    union { float f; unsigned u; } v; v.f = f;
    unsigned r = v.u + 0x7fffu + ((v.u >> 16) & 1u);
    return (u16)(r >> 16);
}
__device__ inline unsigned pack2(float a, float b) {
    return (unsigned)f2bf(a) | ((unsigned)f2bf(b) << 16);
}
__device__ inline void addbf2(unsigned u, float& lo, float& hi) {
    union { unsigned u; float f; } t;
    t.u = u << 16; lo += t.f;
    t.u = u & 0xFFFF0000u; hi += t.f;
}
__device__ inline void bf2(unsigned u, float& lo, float& hi) {
    union { unsigned u; float f; } t;
    t.u = u << 16; lo = t.f;
    t.u = u & 0xFFFF0000u; hi = t.f;
}
__device__ inline uint4 bnrelu_pack(uint4 v, float4 sc0, float4 sc1, float4 sh0, float4 sh1) {
    float x0, x1, x2, x3, x4, x5, x6, x7;
    bf2(v.x, x0, x1); bf2(v.y, x2, x3); bf2(v.z, x4, x5); bf2(v.w, x6, x7);
    x0 = fmaxf(fmaf(x0, sc0.x, sh0.x), 0.f); x1 = fmaxf(fmaf(x1, sc0.y, sh0.y), 0.f);
    x2 = fmaxf(fmaf(x2, sc0.z, sh0.z), 0.f); x3 = fmaxf(fmaf(x3, sc0.w, sh0.w), 0.f);
    x4 = fmaxf(fmaf(x4, sc1.x, sh1.x), 0.f); x5 = fmaxf(fmaf(x5, sc1.y, sh1.y), 0.f);
    x6 = fmaxf(fmaf(x6, sc1.z, sh1.z), 0.f); x7 = fmaxf(fmaf(x7, sc1.w, sh1.w), 0.f);
    uint4 u;
    u.x = pack2(x0, x1); u.y = pack2(x2, x3);
    u.z = pack2(x4, x5); u.w = pack2(x6, x7);
    return u;
}

// ---------------- prologue: convert x, zero deg+stats, build weights/biases ----------------
__global__ __launch_bounds__(256) void prologue(const float* __restrict__ in,
                                                u16* __restrict__ out, int n8,
                                                int* __restrict__ dz, int ndz4,
                                                float* __restrict__ sz, int nsz4,
                                                const float* __restrict__ w1l, const float* __restrict__ w1r,
                                                const float* __restrict__ w2l, const float* __restrict__ w2r,
                                                const float* __restrict__ w3l, const float* __restrict__ w3r,
                                                const float* __restrict__ b2l, const float* __restrict__ b3l,
                                                u16* __restrict__ wt1, u16* __restrict__ wt2,
                                                u16* __restrict__ wt3,
                                                float* __restrict__ bias2, float* __restrict__ bias3) {
    const int tid = blockIdx.x * 256 + threadIdx.x;
    const int stride = gridDim.x * 256;
    int4* d4 = (int4*)dz;
    for (int i = tid; i < ndz4; i += stride) d4[i] = make_int4(0, 0, 0, 0);
    float4* z4 = (float4*)sz;
    for (int i = tid; i < nsz4; i += stride) z4[i] = make_float4(0.f, 0.f, 0.f, 0.f);
    const float4* in4 = (const float4*)in;
    uint4* out4 = (uint4*)out;
    for (int i = tid; i < n8; i += stride) {
        float4 a = in4[2 * i], b = in4[2 * i + 1];
        uint4 u;
        u.x = pack2(a.x, a.y); u.y = pack2(a.z, a.w);
        u.z = pack2(b.x, b.y); u.w = pack2(b.z, b.w);
        out4[i] = u;
    }
    for (int i = tid; i < 213376; i += stride) {
        int idx = i;
        if (idx < 131072) {  // wt1[n][k]: K=512 concat-K
            int n = idx >> 9, k = idx & 511;
            float v = (k < 256) ? w1l[(size_t)k * 256 + n] : w1r[(size_t)(k - 256) * 256 + n];
            wt1[idx] = f2bf(v); continue;
        }
        idx -= 131072;
        if (idx < 65536) {   // wt2[n][k]: concat-N, D=128
            int n = idx >> 8, k = idx & 255;
            float v = (n < 128) ? w2l[(size_t)k * 128 + n] : w2r[(size_t)k * 128 + (n - 128)];
            wt2[idx] = f2bf(v); continue;
        }
        idx -= 65536;
        if (idx < 16384) {   // wt3[n][k]: concat-N, D=64
            int n = idx >> 7, k = idx & 127;
            float v = (n < 64) ? w3l[(size_t)k * 64 + n] : w3r[(size_t)k * 64 + (n - 64)];
            wt3[idx] = f2bf(v); continue;
        }
        idx -= 16384;
        if (idx < 256) { bias2[idx] = (idx < 128) ? 0.f : b2l[idx - 128]; continue; }
        idx -= 256;
        if (idx < 128) { bias3[idx] = (idx < 64) ? 0.f : b3l[idx - 64]; continue; }
    }
}

// ---------------- CSR build ----------------
__global__ void deg_count(const int* __restrict__ dst, int* __restrict__ deg, int E) {
    int i = blockIdx.x * blockDim.x + threadIdx.x;
    if (i < E) atomicAdd(&deg[dst[i]], 1);
}

__global__ __launch_bounds__(256) void scan_phase1(const int* __restrict__ deg,
                                                   int* __restrict__ rowptr,
                                                   int* __restrict__ blocksum, int n) {
    __shared__ int s[256];
    const int t = threadIdx.x;
    const int i = blockIdx.x * 256 + t;
    int d = (i < n) ? deg[i] : 0;
    s[t] = d;
    __syncthreads();
    for (int off = 1; off < 256; off <<= 1) {
        int v = (t >= off) ? s[t - off] : 0;
        __syncthreads();
        s[t] += v;
        __syncthreads();
    }
    if (i < n) rowptr[i] = s[t] - d;
    if (t == 255) blocksum[blockIdx.x] = s[t];
}

__global__ __launch_bounds__(256) void scan_phase2(int* __restrict__ blocksum,
                                                   int* __restrict__ rowptr, int nb, int n) {
    __shared__ int s[256];
    const int t = threadIdx.x;
    int d = (t < nb) ? blocksum[t] : 0;
    s[t] = d;
    __syncthreads();
    for (int off = 1; off < 256; off <<= 1) {
        int v = (t >= off) ? s[t - off] : 0;
        __syncthreads();
        s[t] += v;
        __syncthreads();
    }
    if (t < nb) blocksum[t] = s[t] - d;
    if (t == 255) rowptr[n] = s[t];
}

// also zeroes cursor
__global__ __launch_bounds__(256) void scan_phase3(int* __restrict__ rowptr,
                                                   const int* __restrict__ blocksum,
                                                   const int* __restrict__ deg,
                                                   float* __restrict__ inv,
                                                   int* __restrict__ cursor, int n) {
    int i = blockIdx.x * 256 + threadIdx.x;
    if (i >= n) return;
    rowptr[i] += blocksum[i >> 8];
    inv[i] = 1.0f / fmaxf((float)deg[i], 1.0f);
    cursor[i] = 0;
}

__global__ void csr_fill(const int* __restrict__ src, const int* __restrict__ dst,
                         const int* __restrict__ rowptr, int* __restrict__ cursor,
                         int* __restrict__ csr, int E) {
    int e = blockIdx.x * blockDim.x + threadIdx.x;
    if (e >= E) return;
    int d = dst[e];
    int p = atomicAdd(&cursor[d], 1);
    csr[rowptr[d] + p] = src[e];
}

// ---------------- gather-mean (layer 1): index-prefetch pipeline ----------------
template <int KH>
__global__ __launch_bounds__(256) void gather_mean_bf16(const u16* __restrict__ F,
                                                        const int* __restrict__ rowptr,
                                                        const int* __restrict__ csr,
                                                        const float* __restrict__ inv,
                                                        u16* __restrict__ Sout, int N) {
    constexpr int CG = KH / 8;
    constexpr int NPB = 256 / CG;
    const int c = threadIdx.x % CG;
    const int node = blockIdx.x * NPB + threadIdx.x / CG;
    if (node >= N) return;
    const uint4* F4 = (const uint4*)F;
    float a0 = 0, a1 = 0, a2 = 0, a3 = 0, a4 = 0, a5 = 0, a6 = 0, a7 = 0;
    const int beg = rowptr[node], end = rowptr[node + 1];
    int k = beg;
    if (end - beg >= 4) {
        int i0 = csr[k], i1 = csr[k + 1], i2 = csr[k + 2], i3 = csr[k + 3];
        k += 4;
        for (; k + 3 < end; k += 4) {
            uint4 v0 = F4[(size_t)i0 * CG + c];
            uint4 v1 = F4[(size_t)i1 * CG + c];
            uint4 v2 = F4[(size_t)i2 * CG + c];
            uint4 v3 = F4[(size_t)i3 * CG + c];
            i0 = csr[k]; i1 = csr[k + 1]; i2 = csr[k + 2]; i3 = csr[k + 3];
            addbf2(v0.x, a0, a1); addbf2(v0.y, a2, a3); addbf2(v0.z, a4, a5); addbf2(v0.w, a6, a7);
            addbf2(v1.x, a0, a1); addbf2(v1.y, a2, a3); addbf2(v1.z, a4, a5); addbf2(v1.w, a6, a7);
            addbf2(v2.x, a0, a1); addbf2(v2.y, a2, a3); addbf2(v2.z, a4, a5); addbf2(v2.w, a6, a7);
            addbf2(v3.x, a0, a1); addbf2(v3.y, a2, a3); addbf2(v3.z, a4, a5); addbf2(v3.w, a6, a7);
        }
        uint4 v0 = F4[(size_t)i0 * CG + c];
        uint4 v1 = F4[(size_t)i1 * CG + c];
        uint4 v2 = F4[(size_t)i2 * CG + c];
        uint4 v3 = F4[(size_t)i3 * CG + c];
        addbf2(v0.x, a0, a1); addbf2(v0.y, a2, a3); addbf2(v0.z, a4, a5); addbf2(v0.w, a6, a7);
        addbf2(v1.x, a0, a1); addbf2(v1.y, a2, a3); addbf2(v1.z, a4, a5); addbf2(v1.w, a6, a7);
        addbf2(v2.x, a0, a1); addbf2(v2.y, a2, a3); addbf2(v2.z, a4, a5); addbf2(v2.w, a6, a7);
        addbf2(v3.x, a0, a1); addbf2(v3.y, a2, a3); addbf2(v3.z, a4, a5); addbf2(v3.w, a6, a7);
    }
    for (; k < end; ++k) {
        uint4 v0 = F4[(size_t)csr[k] * CG + c];
        addbf2(v0.x, a0, a1); addbf2(v0.y, a2, a3); addbf2(v0.z, a4, a5); addbf2(v0.w, a6, a7);
    }
    const float w = inv[node];
    uint4 u;
    u.x = pack2(a0 * w, a1 * w); u.y = pack2(a2 * w, a3 * w);
    u.z = pack2(a4 * w, a5 * w); u.w = pack2(a6 * w, a7 * w);
    ((uint4*)Sout)[(size_t)node * CG + c] = u;
}

// ---------------- gather-add (layers 2,3): Hpre = mean-agg(P) + Q, index-prefetch ----------------
template <int D>
__global__ __launch_bounds__(256) void gather_add_bf16(const u16* __restrict__ PQ,
                                                       const int* __restrict__ rowptr,
                                                       const int* __restrict__ csr,
                                                       const float* __restrict__ inv,
                                                       u16* __restrict__ Hpre, int N) {
    constexpr int CG = D / 8;
    constexpr int NPB = 256 / CG;
    constexpr int RS4 = D / 4;
    const int c = threadIdx.x % CG;
    const int node = blockIdx.x * NPB + threadIdx.x / CG;
    if (node >= N) return;
    const uint4* PQ4 = (const uint4*)PQ;
    float a0 = 0, a1 = 0, a2 = 0, a3 = 0, a4 = 0, a5 = 0, a6 = 0, a7 = 0;
    const int beg = rowptr[node], end = rowptr[node + 1];
    int k = beg;
    if (end - beg >= 4) {
        int i0 = csr[k], i1 = csr[k + 1], i2 = csr[k + 2], i3 = csr[k + 3];
        k += 4;
        for (; k + 3 < end; k += 4) {
            uint4 v0 = PQ4[(size_t)i0 * RS4 + c];
            uint4 v1 = PQ4[(size_t)i1 * RS4 + c];
            uint4 v2 = PQ4[(size_t)i2 * RS4 + c];
            uint4 v3 = PQ4[(size_t)i3 * RS4 + c];
            i0 = csr[k]; i1 = csr[k + 1]; i2 = csr[k + 2]; i3 = csr[k + 3];
            addbf2(v0.x, a0, a1); addbf2(v0.y, a2, a3); addbf2(v0.z, a4, a5); addbf2(v0.w, a6, a7);
            addbf2(v1.x, a0, a1); addbf2(v1.y, a2, a3); addbf2(v1.z, a4, a5); addbf2(v1.w, a6, a7);
            addbf2(v2.x, a0, a1); addbf2(v2.y, a2, a3); addbf2(v2.z, a4, a5); addbf2(v2.w, a6, a7);
            addbf2(v3.x, a0, a1); addbf2(v3.y, a2, a3); addbf2(v3.z, a4, a5); addbf2(v3.w, a6, a7);
        }
        uint4 v0 = PQ4[(size_t)i0 * RS4 + c];
        uint4 v1 = PQ4[(size_t)i1 * RS4 + c];
        uint4 v2 = PQ4[(size_t)i2 * RS4 + c];
        uint4 v3 = PQ4[(size_t)i3 * RS4 + c];
        addbf2(v0.x, a0, a1); addbf2(v0.y, a2, a3); addbf2(v0.z, a4, a5); addbf2(v0.w, a6, a7);
        addbf2(v1.x, a0, a1); addbf2(v1.y, a2, a3); addbf2(v1.z, a4, a5); addbf2(v1.w, a6, a7);
        addbf2(v2.x, a0, a1); addbf2(v2.y, a2, a3); addbf2(v2.z, a4, a5); addbf2(v2.w, a6, a7);
        addbf2(v3.x, a0, a1); addbf2(v3.y, a2, a3); addbf2(v3.z, a4, a5); addbf2(v3.w, a6, a7);
    }
    for (; k < end; ++k) {
        uint4 v0 = PQ4[(size_t)csr[k] * RS4 + c];
        addbf2(v0.x, a0, a1); addbf2(v0.y, a2, a3); addbf2(v0.z, a4, a5); addbf2(v0.w, a6, a7);
    }
    const float w = inv[node];
    uint4 q = PQ4[(size_t)node * RS4 + D / 8 + c];
    float q0, q1, q2, q3, q4, q5, q6, q7;
    bf2(q.x, q0, q1); bf2(q.y, q2, q3); bf2(q.z, q4, q5); bf2(q.w, q6, q7);
    uint4 u;
    u.x = pack2(a0 * w + q0, a1 * w + q1);
    u.y = pack2(a2 * w + q2, a3 * w + q3);
    u.z = pack2(a4 * w + q4, a5 * w + q5);
    u.w = pack2(a6 * w + q6, a7 * w + q7);
    ((uint4*)Hpre)[(size_t)node * (D / 8) + c] = u;
}

// ---------------- MFMA GEMM ----------------
template <int KH, int K, int NOUT, bool STATS, bool BNA>
__global__ __launch_bounds__(256, 1) void sage_gemm(const u16* __restrict__ S,
                                                    const u16* __restrict__ X,
                                                    const u16* __restrict__ WT,
                                                    const float* __restrict__ BL,
                                                    const float* __restrict__ SC,
                                                    const float* __restrict__ SH,
                                                    u16* __restrict__ Hb,
                                                    float* __restrict__ sums,
                                                    float* __restrict__ sumsq, int M) {
    constexpr int NK = K / 32;
    constexpr int FN = NOUT / 32;
    constexpr int BUFSZ = 4096 + NOUT * 32;
    __shared__ __align__(16) u16 lds[2][BUFSZ];
    const int t = threadIdx.x;
    const int wid = t >> 6, lane = t & 63;
    const int row0 = blockIdx.x * 128;
    const int wm = wid >> 1, wn = wid & 1;
    const int fr = lane & 15, fc = lane >> 4;
    const int swz8 = (((lane & 3) ^ ((lane >> 3) & 3)) * 8);

    auto stageA_lds = [&](int buf, int ks) {
        const int k0 = ks * 32;
        const u16* srcA;
        int kb;
        if (k0 < KH) { srcA = S; kb = k0; } else { srcA = X; kb = k0 - KH; }
#pragma unroll
        for (int jj = 0; jj < 2; ++jj) {
            int j = wid + jj * 4;
            const u16* g = srcA + (size_t)(row0 + j * 16 + (lane >> 2)) * KH + kb + swz8;
            __builtin_amdgcn_global_load_lds(
                (const __attribute__((address_space(1))) void*)g,
                (__attribute__((address_space(3))) void*)&lds[buf][j * 512], 16, 0, 0);
        }
    };
    auto stageB = [&](int buf, int ks) {
        const int k0 = ks * 32;
#pragma unroll
        for (int jj = 0; jj < NOUT / 64; ++jj) {
            int j = wid * (NOUT / 64) + jj;
            const u16* gb = WT + (size_t)(j * 16 + (lane >> 2)) * K + k0 + swz8;
            __builtin_amdgcn_global_load_lds(
                (const __attribute__((address_space(1))) void*)gb,
                (__attribute__((address_space(3))) void*)&lds[buf][4096 + j * 512], 16, 0, 0);
        }
    };

    uint4 rA[2];
    auto loadA = [&](int ks) {
        const int k0 = ks * 32;
#pragma unroll
        for (int jj = 0; jj < 2; ++jj) {
            int j = wid + jj * 4;
            rA[jj] = *(const uint4*)(S + (size_t)(row0 + j * 16 + (lane >> 2)) * KH + k0 + swz8);
        }
    };
    auto writeA = [&](int buf, int ks) {
        const int k0 = ks * 32;
        float4 sc0 = *(const float4*)&SC[k0 + swz8];
        float4 sc1 = *(const float4*)&SC[k0 + swz8 + 4];
        float4 sh0 = *(const float4*)&SH[k0 + swz8];
        float4 sh1 = *(const float4*)&SH[k0 + swz8 + 4];
#pragma unroll
        for (int jj = 0; jj < 2; ++jj) {
            int j = wid + jj * 4;
            *(uint4*)&lds[buf][(size_t)j * 512 + lane * 8] = bnrelu_pack(rA[jj], sc0, sc1, sh0, sh1);
        }
    };

    f32x4 acc[4][FN] = {};

    auto compute = [&](int buf) {
        const u16* A = &lds[buf][0];
        const u16* B = &lds[buf][4096];
        const int swr = (fr >> 1) & 3;
        const int kc = (fc ^ swr) * 8;
        bf16x8 a[4], b[FN];
#pragma unroll
        for (int fm = 0; fm < 4; ++fm)
            a[fm] = *(const bf16x8*)&A[(wm * 64 + fm * 16 + fr) * 32 + kc];
#pragma unroll
        for (int fn = 0; fn < FN; ++fn)
            b[fn] = *(const bf16x8*)&B[(wn * (NOUT / 2) + fn * 16 + fr) * 32 + kc];
#pragma unroll
        for (int fm = 0; fm < 4; ++fm)
#pragma unroll
            for (int fn = 0; fn < FN; ++fn)
                acc[fm][fn] = __builtin_amdgcn_mfma_f32_16x16x32_bf16(a[fm], b[fn], acc[fm][fn], 0, 0, 0);
    };

    if constexpr (BNA) {
        static_assert(KH == K, "BNA requires single operand");
        loadA(0);
        writeA(0, 0);
        stageB(0, 0);
        if (NK > 1) loadA(1);
        for (int ks = 0; ks < NK; ++ks) {
            __syncthreads();
            if (ks + 1 < NK) {
                writeA((ks + 1) & 1, ks + 1);
                stageB((ks + 1) & 1, ks + 1);
                if (ks + 2 < NK) loadA(ks + 2);
            }
            compute(ks & 1);
        }
    } else {
        stageA_lds(0, 0);
        stageB(0, 0);
        for (int ks = 0; ks < NK; ++ks) {
            __syncthreads();
            if (ks + 1 < NK) {
                stageA_lds((ks + 1) & 1, ks + 1);
                stageB((ks + 1) & 1, ks + 1);
            }
            compute(ks & 1);
        }
    }

    const int cw = wn * (NOUT / 2);
    float bias[FN], s[FN], ss[FN];
#pragma unroll
    for (int fn = 0; fn < FN; ++fn) {
        bias[fn] = BL[cw + fn * 16 + fr];
        s[fn] = 0.f; ss[fn] = 0.f;
    }
#pragma unroll
    for (int fm = 0; fm < 4; ++fm) {
#pragma unroll
        for (int q = 0; q < 4; ++q) {
            int r = row0 + wm * 64 + fm * 16 + fc * 4 + q;
            if (r < M) {
#pragma unroll
                for (int fn = 0; fn < FN; ++fn) {
                    float h = acc[fm][fn][q] + bias[fn];
                    Hb[(size_t)r * NOUT + cw + fn * 16 + fr] = f2bf(h);
                    if constexpr (STATS) { s[fn] += h; ss[fn] += h * h; }
                }
            }
        }
    }
    if constexpr (STATS) {
#pragma unroll
        for (int fn = 0; fn < FN; ++fn) {
            float sv = s[fn], sq = ss[fn];
            sv += __shfl_xor(sv, 16); sv += __shfl_xor(sv, 32);
            sq += __shfl_xor(sq, 16); sq += __shfl_xor(sq, 32);
            if (fc == 0) {
                atomicAdd(&sums[cw + fn * 16 + fr], sv);
                atomicAdd(&sumsq[cw + fn * 16 + fr], sq);
            }
        }
    }
}

// ---------------- BN column stats (vectorized two-level) ----------------
template <int M>
__global__ __launch_bounds__(256) void col_stats_fast(const u16* __restrict__ H,
                                                      float* __restrict__ sums,
                                                      float* __restrict__ sumsq, int nrows) {
    constexpr int C4 = M / 8;
    constexpr int RPB = 256 / C4;
    __shared__ float ls[M], lss[M];
    for (int j = threadIdx.x; j < M; j += 256) { ls[j] = 0.f; lss[j] = 0.f; }
    __syncthreads();
    const int c = threadIdx.x % C4;
    const int rg = threadIdx.x / C4;
    float s[8] = {}, ss[8] = {};
    const uint4* H4 = (const uint4*)H;
    for (int r = blockIdx.x * RPB + rg; r < nrows; r += gridDim.x * RPB) {
        uint4 v = H4[(size_t)r * C4 + c];
        float x0, x1, x2, x3, x4, x5, x6, x7;
        bf2(v.x, x0, x1); bf2(v.y, x2, x3); bf2(v.z, x4, x5); bf2(v.w, x6, x7);
        s[0] += x0; ss[0] += x0 * x0;  s[1] += x1; ss[1] += x1 * x1;
        s[2] += x2; ss[2] += x2 * x2;  s[3] += x3; ss[3] += x3 * x3;
        s[4] += x4; ss[4] += x4 * x4;  s[5] += x5; ss[5] += x5 * x5;
        s[6] += x6; ss[6] += x6 * x6;  s[7] += x7; ss[7] += x7 * x7;
    }
#pragma unroll
    for (int j = 0; j < 8; ++j) {
        atomicAdd(&ls[c * 8 + j], s[j]);
        atomicAdd(&lss[c * 8 + j], ss[j]);
    }
    __syncthreads();
    for (int j = threadIdx.x; j < M; j += 256) {
        atomicAdd(&sums[j], ls[j]);
        atomicAdd(&sumsq[j], lss[j]);
    }
}

// ---------------- BN finalize ----------------
template <int M>
__global__ void bn_finalize(const float* __restrict__ sums, const float* __restrict__ sumsq,
                            const float* __restrict__ g, const float* __restrict__ beta,
                            float* __restrict__ scale, float* __restrict__ shift, int nrows) {
    int j = threadIdx.x;
    if (j >= M) return;
    float mean = sums[j] / nrows;
    float var = fmaxf(sumsq[j] / nrows - mean * mean, 0.f);
    float sc = g[j] * rsqrtf(var + BN_EPS);
    scale[j] = sc;
    shift[j] = beta[j] - mean * sc;
}

// ---------------- head with fused BN3+ReLU ----------------
__global__ __launch_bounds__(256) void head_bn(const u16* __restrict__ H3pre,
                                               const float* __restrict__ sc,
                                               const float* __restrict__ sh,
                                               const float* __restrict__ wh,
                                               const float* __restrict__ bh,
                                               float* __restrict__ out, int n) {
    int i = blockIdx.x * blockDim.x + threadIdx.x;
    if (i >= n) return;
    const uint4* h4 = (const uint4*)(H3pre + (size_t)i * 64);
    float acc = bh[0];
#pragma unroll
    for (int c = 0; c < 8; ++c) {
        uint4 v = h4[c];
        float x0, x1, x2, x3, x4, x5, x6, x7;
        bf2(v.x, x0, x1); bf2(v.y, x2, x3); bf2(v.z, x4, x5); bf2(v.w, x6, x7);
        const float* s = sc + c * 8;
        const float* t = sh + c * 8;
        const float* w = wh + c * 8;
        acc += fmaxf(fmaf(x0, s[0], t[0]), 0.f) * w[0];
        acc += fmaxf(fmaf(x1, s[1], t[1]), 0.f) * w[1];
        acc += fmaxf(fmaf(x2, s[2], t[2]), 0.f) * w[2];
        acc += fmaxf(fmaf(x3, s[3], t[3]), 0.f) * w[3];
        acc += fmaxf(fmaf(x4, s[4], t[4]), 0.f) * w[4];
        acc += fmaxf(fmaf(x5, s[5], t[5]), 0.f) * w[5];
        acc += fmaxf(fmaf(x6, s[6], t[6]), 0.f) * w[6];
        acc += fmaxf(fmaf(x7, s[7], t[7]), 0.f) * w[7];
    }
    out[i] = acc;
}

// ---------------- launch ----------------
extern "C" void kernel_launch(void* const* d_in, const int* in_sizes, int n_in,
                              void* d_out, int out_size, void* d_ws, size_t ws_size,
                              hipStream_t stream) {
    const int N = N_NODES, E = N_EDGES;
    const float* x   = (const float*)d_in[0];
    const int*   ei  = (const int*)d_in[1];
    const int*   src = ei;
    const int*   dst = ei + E;
    const float* w1l = (const float*)d_in[2];
    const float* b1l = (const float*)d_in[3];
    const float* w1r = (const float*)d_in[4];
    const float* g1  = (const float*)d_in[5];
    const float* be1 = (const float*)d_in[6];
    const float* w2l = (const float*)d_in[7];
    const float* b2l = (const float*)d_in[8];
    const float* w2r = (const float*)d_in[9];
    const float* g2  = (const float*)d_in[10];
    const float* be2 = (const float*)d_in[11];
    const float* w3l = (const float*)d_in[12];
    const float* b3l = (const float*)d_in[13];
    const float* w3r = (const float*)d_in[14];
    const float* g3  = (const float*)d_in[15];
    const float* be3 = (const float*)d_in[16];
    const float* wh  = (const float*)d_in[17];
    const float* bh  = (const float*)d_in[18];
    float* out = (float*)d_out;

    // ---- workspace layout ----
    char* base = (char*)d_ws;
    size_t off = 0;
    auto alloc = [&](size_t bytes) -> void* {
        void* r = base + off;
        off += (bytes + 255) & ~(size_t)255;
        return r;
    };
    const int NB = (N + 255) / 256;  // 196
    int*   rowptr = (int*)alloc((N + 8) * sizeof(int));
    int*   csr    = (int*)alloc((size_t)E * sizeof(int));
    int*   deg_i  = (int*)alloc(N * sizeof(int));
    int*   cursor = (int*)alloc(N * sizeof(int));
    int*   bsum   = (int*)alloc(256 * sizeof(int));
    float* inv    = (float*)alloc(N * sizeof(float));
    u16*   xb     = (u16*)alloc((size_t)NP * 256 * 2);
    u16*   sB     = (u16*)alloc((size_t)NP * 256 * 2);
    u16*   hpre1  = (u16*)alloc((size_t)NP * 256 * 2);
    u16*   hpre2  = (u16*)alloc((size_t)NP * 256 * 2);   // [P|Q] layer 2
    u16*   h2pre  = (u16*)alloc((size_t)NP * 128 * 2);
    u16*   hpre3  = (u16*)alloc((size_t)NP * 128 * 2);   // [P|Q] layer 3
    u16*   h3pre  = (u16*)alloc((size_t)NP * 64 * 2);
    u16*   wt1    = (u16*)alloc((size_t)131072 * 2);
    u16*   wt2    = (u16*)alloc((size_t)65536 * 2);
    u16*   wt3    = (u16*)alloc((size_t)16384 * 2);
    // stats: zeroed prefix [sums1 256][sumsq1 256][sums2 128][sumsq2 128]
    //        [sums3 64][sumsq3 64] = 896; then scale/shift (896)
    const int ZFLOATS = 896;
    float* stats  = (float*)alloc((ZFLOATS + 896) * sizeof(float));
    float* sums1 = stats,       *sumsq1 = stats + 256;
    float* sums2 = stats + 512, *sumsq2 = stats + 640;
    float* sums3 = stats + 768, *sumsq3 = stats + 832;
    float* post   = stats + ZFLOATS;
    float* scale1 = post,       *shift1 = post + 256;
    float* scale2 = post + 512, *shift2 = post + 640;
    float* scale3 = post + 768, *shift3 = post + 832;
    float* bias2  = (float*)alloc(256 * sizeof(float));
    float* bias3  = (float*)alloc(128 * sizeof(float));

    const int MB = NP / 128;  // 391

    // prologue: convert x, zero deg+stats, build weights/biases
    prologue<<<2048, 256, 0, stream>>>(x, xb, N * 256 / 8, deg_i, N / 4,
                                       stats, ZFLOATS / 4,
                                       w1l, w1r, w2l, w2r, w3l, w3r, b2l, b3l,
                                       wt1, wt2, wt3, bias2, bias3);

    // CSR build
    deg_count<<<(E + 255) / 256, 256, 0, stream>>>(dst, deg_i, E);
    scan_phase1<<<NB, 256, 0, stream>>>(deg_i, rowptr, bsum, N);
    scan_phase2<<<1, 256, 0, stream>>>(bsum, rowptr, NB, N);
    scan_phase3<<<NB, 256, 0, stream>>>(rowptr, bsum, deg_i, inv, cursor, N);
    csr_fill<<<(E + 255) / 256, 256, 0, stream>>>(src, dst, rowptr, cursor, csr, E);

    // layer 1: agg-first, [S|X] K=512 -> 256, stats fused in GEMM epilogue
    gather_mean_bf16<256><<<(N * 32 + 255) / 256, 256, 0, stream>>>(xb, rowptr, csr, inv, sB, N);
    sage_gemm<256, 512, 256, true, false><<<MB, 256, 0, stream>>>(
        sB, xb, wt1, b1l, nullptr, nullptr, hpre1, sums1, sumsq1, N);
    bn_finalize<256><<<1, 256, 0, stream>>>(sums1, sumsq1, g1, be1, scale1, shift1, N);

    // layer 2: transform-first, BN1+ReLU fused into A staging
    sage_gemm<256, 256, 256, false, true><<<MB, 256, 0, stream>>>(
        hpre1, hpre1, wt2, bias2, scale1, shift1, hpre2, nullptr, nullptr, N);
    gather_add_bf16<128><<<(N * 16 + 255) / 256, 256, 0, stream>>>(hpre2, rowptr, csr, inv, h2pre, N);
    col_stats_fast<128><<<256, 256, 0, stream>>>(h2pre, sums2, sumsq2, N);
    bn_finalize<128><<<1, 128, 0, stream>>>(sums2, sumsq2, g2, be2, scale2, shift2, N);

    // layer 3: transform-first, BN2+ReLU fused into A staging
    sage_gemm<128, 128, 128, false, true><<<MB, 256, 0, stream>>>(
        h2pre, h2pre, wt3, bias3, scale2, shift2, hpre3, nullptr, nullptr, N);
    gather_add_bf16<64><<<(N * 8 + 255) / 256, 256, 0, stream>>>(hpre3, rowptr, csr, inv, h3pre, N);
    col_stats_fast<64><<<256, 256, 0, stream>>>(h3pre, sums3, sumsq3, N);
    bn_finalize<64><<<1, 64, 0, stream>>>(sums3, sumsq3, g3, be3, scale3, shift3, N);

    // head with fused BN3+ReLU
    head_bn<<<(N + 255) / 256, 256, 0, stream>>>(h3pre, scale3, shift3, wh, bh, out, N);
}

// Round 13
// 301.559 us; speedup vs baseline: 2.4665x; 1.0389x over previous
//
#include <hip/hip_runtime.h>
#include <cstddef>
#include <cstdint>

#define N_NODES 50000
#define N_EDGES 800000
#define NP 50048   // 391 * 128, padded row count
static constexpr float BN_EPS = 1e-5f;

typedef unsigned short u16;
typedef short bf16x8 __attribute__((ext_vector_type(8)));
typedef float f32x4 __attribute__((ext_vector_type(4)));

// ---------------- helpers ----------------
__device__ inline u16 f2bf(float f) {
    union { float f; unsigned u; } v; v.f = f;
    unsigned r = v.u + 0x7fffu + ((v.u >> 16) & 1u);
    return (u16)(r >> 16);
}
__device__ inline unsigned pack2(float a, float b) {
    return (unsigned)f2bf(a) | ((unsigned)f2bf(b) << 16);
}
__device__ inline void addbf2(unsigned u, float& lo, float& hi) {
    union { unsigned u; float f; } t;
    t.u = u << 16; lo += t.f;
    t.u = u & 0xFFFF0000u; hi += t.f;
}
__device__ inline void bf2(unsigned u, float& lo, float& hi) {
    union { unsigned u; float f; } t;
    t.u = u << 16; lo = t.f;
    t.u = u & 0xFFFF0000u; hi = t.f;
}
__device__ inline uint4 bnrelu_pack(uint4 v, float4 sc0, float4 sc1, float4 sh0, float4 sh1) {
    float x0, x1, x2, x3, x4, x5, x6, x7;
    bf2(v.x, x0, x1); bf2(v.y, x2, x3); bf2(v.z, x4, x5); bf2(v.w, x6, x7);
    x0 = fmaxf(fmaf(x0, sc0.x, sh0.x), 0.f); x1 = fmaxf(fmaf(x1, sc0.y, sh0.y), 0.f);
    x2 = fmaxf(fmaf(x2, sc0.z, sh0.z), 0.f); x3 = fmaxf(fmaf(x3, sc0.w, sh0.w), 0.f);
    x4 = fmaxf(fmaf(x4, sc1.x, sh1.x), 0.f); x5 = fmaxf(fmaf(x5, sc1.y, sh1.y), 0.f);
    x6 = fmaxf(fmaf(x6, sc1.z, sh1.z), 0.f); x7 = fmaxf(fmaf(x7, sc1.w, sh1.w), 0.f);
    uint4 u;
    u.x = pack2(x0, x1); u.y = pack2(x2, x3);
    u.z = pack2(x4, x5); u.w = pack2(x6, x7);
    return u;
}

// ---------------- prologue: convert x, zero deg+stats, build weights/biases ----------------
__global__ __launch_bounds__(256) void prologue(const float* __restrict__ in,
                                                u16* __restrict__ out, int n8,
                                                int* __restrict__ dz, int ndz4,
                                                float* __restrict__ sz, int nsz4,
                                                const float* __restrict__ w1l, const float* __restrict__ w1r,
                                                const float* __restrict__ w2l, const float* __restrict__ w2r,
                                                const float* __restrict__ w3l, const float* __restrict__ w3r,
                                                const float* __restrict__ b2l, const float* __restrict__ b3l,
                                                u16* __restrict__ wt1, u16* __restrict__ wt2,
                                                u16* __restrict__ wt3,
                                                float* __restrict__ bias2, float* __restrict__ bias3) {
    const int tid = blockIdx.x * 256 + threadIdx.x;
    const int stride = gridDim.x * 256;
    int4* d4 = (int4*)dz;
    for (int i = tid; i < ndz4; i += stride) d4[i] = make_int4(0, 0, 0, 0);
    float4* z4 = (float4*)sz;
    for (int i = tid; i < nsz4; i += stride) z4[i] = make_float4(0.f, 0.f, 0.f, 0.f);
    const float4* in4 = (const float4*)in;
    uint4* out4 = (uint4*)out;
    for (int i = tid; i < n8; i += stride) {
        float4 a = in4[2 * i], b = in4[2 * i + 1];
        uint4 u;
        u.x = pack2(a.x, a.y); u.y = pack2(a.z, a.w);
        u.z = pack2(b.x, b.y); u.w = pack2(b.z, b.w);
        out4[i] = u;
    }
    for (int i = tid; i < 213376; i += stride) {
        int idx = i;
        if (idx < 131072) {  // wt1[n][k]: K=512 concat-K
            int n = idx >> 9, k = idx & 511;
            float v = (k < 256) ? w1l[(size_t)k * 256 + n] : w1r[(size_t)(k - 256) * 256 + n];
            wt1[idx] = f2bf(v); continue;
        }
        idx -= 131072;
        if (idx < 65536) {   // wt2[n][k]: concat-N, D=128
            int n = idx >> 8, k = idx & 255;
            float v = (n < 128) ? w2l[(size_t)k * 128 + n] : w2r[(size_t)k * 128 + (n - 128)];
            wt2[idx] = f2bf(v); continue;
        }
        idx -= 65536;
        if (idx < 16384) {   // wt3[n][k]: concat-N, D=64
            int n = idx >> 7, k = idx & 127;
            float v = (n < 64) ? w3l[(size_t)k * 64 + n] : w3r[(size_t)k * 64 + (n - 64)];
            wt3[idx] = f2bf(v); continue;
        }
        idx -= 16384;
        if (idx < 256) { bias2[idx] = (idx < 128) ? 0.f : b2l[idx - 128]; continue; }
        idx -= 256;
        if (idx < 128) { bias3[idx] = (idx < 64) ? 0.f : b3l[idx - 64]; continue; }
    }
}

// ---------------- CSR build ----------------
__global__ void deg_count(const int* __restrict__ dst, int* __restrict__ deg, int E) {
    int i = blockIdx.x * blockDim.x + threadIdx.x;
    if (i < E) atomicAdd(&deg[dst[i]], 1);
}

__global__ __launch_bounds__(256) void scan_phase1(const int* __restrict__ deg,
                                                   int* __restrict__ rowptr,
                                                   int* __restrict__ blocksum, int n) {
    __shared__ int s[256];
    const int t = threadIdx.x;
    const int i = blockIdx.x * 256 + t;
    int d = (i < n) ? deg[i] : 0;
    s[t] = d;
    __syncthreads();
    for (int off = 1; off < 256; off <<= 1) {
        int v = (t >= off) ? s[t - off] : 0;
        __syncthreads();
        s[t] += v;
        __syncthreads();
    }
    if (i < n) rowptr[i] = s[t] - d;
    if (t == 255) blocksum[blockIdx.x] = s[t];
}

__global__ __launch_bounds__(256) void scan_phase2(int* __restrict__ blocksum,
                                                   int* __restrict__ rowptr, int nb, int n) {
    __shared__ int s[256];
    const int t = threadIdx.x;
    int d = (t < nb) ? blocksum[t] : 0;
    s[t] = d;
    __syncthreads();
    for (int off = 1; off < 256; off <<= 1) {
        int v = (t >= off) ? s[t - off] : 0;
        __syncthreads();
        s[t] += v;
        __syncthreads();
    }
    if (t < nb) blocksum[t] = s[t] - d;
    if (t == 255) rowptr[n] = s[t];
}

// also zeroes cursor
__global__ __launch_bounds__(256) void scan_phase3(int* __restrict__ rowptr,
                                                   const int* __restrict__ blocksum,
                                                   const int* __restrict__ deg,
                                                   float* __restrict__ inv,
                                                   int* __restrict__ cursor, int n) {
    int i = blockIdx.x * 256 + threadIdx.x;
    if (i >= n) return;
    rowptr[i] += blocksum[i >> 8];
    inv[i] = 1.0f / fmaxf((float)deg[i], 1.0f);
    cursor[i] = 0;
}

__global__ void csr_fill(const int* __restrict__ src, const int* __restrict__ dst,
                         const int* __restrict__ rowptr, int* __restrict__ cursor,
                         int* __restrict__ csr, int E) {
    int e = blockIdx.x * blockDim.x + threadIdx.x;
    if (e >= E) return;
    int d = dst[e];
    int p = atomicAdd(&cursor[d], 1);
    csr[rowptr[d] + p] = src[e];
}

// ---------------- gather-mean (layer 1): index-prefetch pipeline ----------------
template <int KH>
__global__ __launch_bounds__(256) void gather_mean_bf16(const u16* __restrict__ F,
                                                        const int* __restrict__ rowptr,
                                                        const int* __restrict__ csr,
                                                        const float* __restrict__ inv,
                                                        u16* __restrict__ Sout, int N) {
    constexpr int CG = KH / 8;
    constexpr int NPB = 256 / CG;
    const int c = threadIdx.x % CG;
    const int node = blockIdx.x * NPB + threadIdx.x / CG;
    if (node >= N) return;
    const uint4* F4 = (const uint4*)F;
    float a0 = 0, a1 = 0, a2 = 0, a3 = 0, a4 = 0, a5 = 0, a6 = 0, a7 = 0;
    const int beg = rowptr[node], end = rowptr[node + 1];
    int k = beg;
    if (end - beg >= 4) {
        int i0 = csr[k], i1 = csr[k + 1], i2 = csr[k + 2], i3 = csr[k + 3];
        k += 4;
        for (; k + 3 < end; k += 4) {
            uint4 v0 = F4[(size_t)i0 * CG + c];
            uint4 v1 = F4[(size_t)i1 * CG + c];
            uint4 v2 = F4[(size_t)i2 * CG + c];
            uint4 v3 = F4[(size_t)i3 * CG + c];
            i0 = csr[k]; i1 = csr[k + 1]; i2 = csr[k + 2]; i3 = csr[k + 3];
            addbf2(v0.x, a0, a1); addbf2(v0.y, a2, a3); addbf2(v0.z, a4, a5); addbf2(v0.w, a6, a7);
            addbf2(v1.x, a0, a1); addbf2(v1.y, a2, a3); addbf2(v1.z, a4, a5); addbf2(v1.w, a6, a7);
            addbf2(v2.x, a0, a1); addbf2(v2.y, a2, a3); addbf2(v2.z, a4, a5); addbf2(v2.w, a6, a7);
            addbf2(v3.x, a0, a1); addbf2(v3.y, a2, a3); addbf2(v3.z, a4, a5); addbf2(v3.w, a6, a7);
        }
        uint4 v0 = F4[(size_t)i0 * CG + c];
        uint4 v1 = F4[(size_t)i1 * CG + c];
        uint4 v2 = F4[(size_t)i2 * CG + c];
        uint4 v3 = F4[(size_t)i3 * CG + c];
        addbf2(v0.x, a0, a1); addbf2(v0.y, a2, a3); addbf2(v0.z, a4, a5); addbf2(v0.w, a6, a7);
        addbf2(v1.x, a0, a1); addbf2(v1.y, a2, a3); addbf2(v1.z, a4, a5); addbf2(v1.w, a6, a7);
        addbf2(v2.x, a0, a1); addbf2(v2.y, a2, a3); addbf2(v2.z, a4, a5); addbf2(v2.w, a6, a7);
        addbf2(v3.x, a0, a1); addbf2(v3.y, a2, a3); addbf2(v3.z, a4, a5); addbf2(v3.w, a6, a7);
    }
    for (; k < end; ++k) {
        uint4 v0 = F4[(size_t)csr[k] * CG + c];
        addbf2(v0.x, a0, a1); addbf2(v0.y, a2, a3); addbf2(v0.z, a4, a5); addbf2(v0.w, a6, a7);
    }
    const float w = inv[node];
    uint4 u;
    u.x = pack2(a0 * w, a1 * w); u.y = pack2(a2 * w, a3 * w);
    u.z = pack2(a4 * w, a5 * w); u.w = pack2(a6 * w, a7 * w);
    ((uint4*)Sout)[(size_t)node * CG + c] = u;
}

// ---------------- gather-add (layers 2,3): Hpre = mean-agg(P) + Q, index-prefetch ----------------
template <int D>
__global__ __launch_bounds__(256) void gather_add_bf16(const u16* __restrict__ PQ,
                                                       const int* __restrict__ rowptr,
                                                       const int* __restrict__ csr,
                                                       const float* __restrict__ inv,
                                                       u16* __restrict__ Hpre, int N) {
    constexpr int CG = D / 8;
    constexpr int NPB = 256 / CG;
    constexpr int RS4 = D / 4;
    const int c = threadIdx.x % CG;
    const int node = blockIdx.x * NPB + threadIdx.x / CG;
    if (node >= N) return;
    const uint4* PQ4 = (const uint4*)PQ;
    float a0 = 0, a1 = 0, a2 = 0, a3 = 0, a4 = 0, a5 = 0, a6 = 0, a7 = 0;
    const int beg = rowptr[node], end = rowptr[node + 1];
    int k = beg;
    if (end - beg >= 4) {
        int i0 = csr[k], i1 = csr[k + 1], i2 = csr[k + 2], i3 = csr[k + 3];
        k += 4;
        for (; k + 3 < end; k += 4) {
            uint4 v0 = PQ4[(size_t)i0 * RS4 + c];
            uint4 v1 = PQ4[(size_t)i1 * RS4 + c];
            uint4 v2 = PQ4[(size_t)i2 * RS4 + c];
            uint4 v3 = PQ4[(size_t)i3 * RS4 + c];
            i0 = csr[k]; i1 = csr[k + 1]; i2 = csr[k + 2]; i3 = csr[k + 3];
            addbf2(v0.x, a0, a1); addbf2(v0.y, a2, a3); addbf2(v0.z, a4, a5); addbf2(v0.w, a6, a7);
            addbf2(v1.x, a0, a1); addbf2(v1.y, a2, a3); addbf2(v1.z, a4, a5); addbf2(v1.w, a6, a7);
            addbf2(v2.x, a0, a1); addbf2(v2.y, a2, a3); addbf2(v2.z, a4, a5); addbf2(v2.w, a6, a7);
            addbf2(v3.x, a0, a1); addbf2(v3.y, a2, a3); addbf2(v3.z, a4, a5); addbf2(v3.w, a6, a7);
        }
        uint4 v0 = PQ4[(size_t)i0 * RS4 + c];
        uint4 v1 = PQ4[(size_t)i1 * RS4 + c];
        uint4 v2 = PQ4[(size_t)i2 * RS4 + c];
        uint4 v3 = PQ4[(size_t)i3 * RS4 + c];
        addbf2(v0.x, a0, a1); addbf2(v0.y, a2, a3); addbf2(v0.z, a4, a5); addbf2(v0.w, a6, a7);
        addbf2(v1.x, a0, a1); addbf2(v1.y, a2, a3); addbf2(v1.z, a4, a5); addbf2(v1.w, a6, a7);
        addbf2(v2.x, a0, a1); addbf2(v2.y, a2, a3); addbf2(v2.z, a4, a5); addbf2(v2.w, a6, a7);
        addbf2(v3.x, a0, a1); addbf2(v3.y, a2, a3); addbf2(v3.z, a4, a5); addbf2(v3.w, a6, a7);
    }
    for (; k < end; ++k) {
        uint4 v0 = PQ4[(size_t)csr[k] * RS4 + c];
        addbf2(v0.x, a0, a1); addbf2(v0.y, a2, a3); addbf2(v0.z, a4, a5); addbf2(v0.w, a6, a7);
    }
    const float w = inv[node];
    uint4 q = PQ4[(size_t)node * RS4 + D / 8 + c];
    float q0, q1, q2, q3, q4, q5, q6, q7;
    bf2(q.x, q0, q1); bf2(q.y, q2, q3); bf2(q.z, q4, q5); bf2(q.w, q6, q7);
    uint4 u;
    u.x = pack2(a0 * w + q0, a1 * w + q1);
    u.y = pack2(a2 * w + q2, a3 * w + q3);
    u.z = pack2(a4 * w + q4, a5 * w + q5);
    u.w = pack2(a6 * w + q6, a7 * w + q7);
    ((uint4*)Hpre)[(size_t)node * (D / 8) + c] = u;
}

// ---------------- MFMA GEMM ----------------
// __launch_bounds__(256, 2): cap VGPR at 256 so 2 blocks/CU are co-resident —
// overlaps the per-K-step vmcnt(0) barrier drain across blocks and makes
// grid=391 fit in one round (512 slots on 256 CUs).
template <int KH, int K, int NOUT, bool STATS, bool BNA>
__global__ __launch_bounds__(256, 2) void sage_gemm(const u16* __restrict__ S,
                                                    const u16* __restrict__ X,
                                                    const u16* __restrict__ WT,
                                                    const float* __restrict__ BL,
                                                    const float* __restrict__ SC,
                                                    const float* __restrict__ SH,
                                                    u16* __restrict__ Hb,
                                                    float* __restrict__ sums,
                                                    float* __restrict__ sumsq, int M) {
    constexpr int NK = K / 32;
    constexpr int FN = NOUT / 32;
    constexpr int BUFSZ = 4096 + NOUT * 32;
    __shared__ __align__(16) u16 lds[2][BUFSZ];
    const int t = threadIdx.x;
    const int wid = t >> 6, lane = t & 63;
    const int row0 = blockIdx.x * 128;
    const int wm = wid >> 1, wn = wid & 1;
    const int fr = lane & 15, fc = lane >> 4;
    const int swz8 = (((lane & 3) ^ ((lane >> 3) & 3)) * 8);

    auto stageA_lds = [&](int buf, int ks) {
        const int k0 = ks * 32;
        const u16* srcA;
        int kb;
        if (k0 < KH) { srcA = S; kb = k0; } else { srcA = X; kb = k0 - KH; }
#pragma unroll
        for (int jj = 0; jj < 2; ++jj) {
            int j = wid + jj * 4;
            const u16* g = srcA + (size_t)(row0 + j * 16 + (lane >> 2)) * KH + kb + swz8;
            __builtin_amdgcn_global_load_lds(
                (const __attribute__((address_space(1))) void*)g,
                (__attribute__((address_space(3))) void*)&lds[buf][j * 512], 16, 0, 0);
        }
    };
    auto stageB = [&](int buf, int ks) {
        const int k0 = ks * 32;
#pragma unroll
        for (int jj = 0; jj < NOUT / 64; ++jj) {
            int j = wid * (NOUT / 64) + jj;
            const u16* gb = WT + (size_t)(j * 16 + (lane >> 2)) * K + k0 + swz8;
            __builtin_amdgcn_global_load_lds(
                (const __attribute__((address_space(1))) void*)gb,
                (__attribute__((address_space(3))) void*)&lds[buf][4096 + j * 512], 16, 0, 0);
        }
    };

    uint4 rA[2];
    auto loadA = [&](int ks) {
        const int k0 = ks * 32;
#pragma unroll
        for (int jj = 0; jj < 2; ++jj) {
            int j = wid + jj * 4;
            rA[jj] = *(const uint4*)(S + (size_t)(row0 + j * 16 + (lane >> 2)) * KH + k0 + swz8);
        }
    };
    auto writeA = [&](int buf, int ks) {
        const int k0 = ks * 32;
        float4 sc0 = *(const float4*)&SC[k0 + swz8];
        float4 sc1 = *(const float4*)&SC[k0 + swz8 + 4];
        float4 sh0 = *(const float4*)&SH[k0 + swz8];
        float4 sh1 = *(const float4*)&SH[k0 + swz8 + 4];
#pragma unroll
        for (int jj = 0; jj < 2; ++jj) {
            int j = wid + jj * 4;
            *(uint4*)&lds[buf][(size_t)j * 512 + lane * 8] = bnrelu_pack(rA[jj], sc0, sc1, sh0, sh1);
        }
    };

    f32x4 acc[4][FN] = {};

    auto compute = [&](int buf) {
        const u16* A = &lds[buf][0];
        const u16* B = &lds[buf][4096];
        const int swr = (fr >> 1) & 3;
        const int kc = (fc ^ swr) * 8;
        bf16x8 a[4], b[FN];
#pragma unroll
        for (int fm = 0; fm < 4; ++fm)
            a[fm] = *(const bf16x8*)&A[(wm * 64 + fm * 16 + fr) * 32 + kc];
#pragma unroll
        for (int fn = 0; fn < FN; ++fn)
            b[fn] = *(const bf16x8*)&B[(wn * (NOUT / 2) + fn * 16 + fr) * 32 + kc];
#pragma unroll
        for (int fm = 0; fm < 4; ++fm)
#pragma unroll
            for (int fn = 0; fn < FN; ++fn)
                acc[fm][fn] = __builtin_amdgcn_mfma_f32_16x16x32_bf16(a[fm], b[fn], acc[fm][fn], 0, 0, 0);
    };

    if constexpr (BNA) {
        static_assert(KH == K, "BNA requires single operand");
        loadA(0);
        writeA(0, 0);
        stageB(0, 0);
        if (NK > 1) loadA(1);
        for (int ks = 0; ks < NK; ++ks) {
            __syncthreads();
            if (ks + 1 < NK) {
                writeA((ks + 1) & 1, ks + 1);
                stageB((ks + 1) & 1, ks + 1);
                if (ks + 2 < NK) loadA(ks + 2);
            }
            compute(ks & 1);
        }
    } else {
        stageA_lds(0, 0);
        stageB(0, 0);
        for (int ks = 0; ks < NK; ++ks) {
            __syncthreads();
            if (ks + 1 < NK) {
                stageA_lds((ks + 1) & 1, ks + 1);
                stageB((ks + 1) & 1, ks + 1);
            }
            compute(ks & 1);
        }
    }

    const int cw = wn * (NOUT / 2);
    float bias[FN], s[FN], ss[FN];
#pragma unroll
    for (int fn = 0; fn < FN; ++fn) {
        bias[fn] = BL[cw + fn * 16 + fr];
        s[fn] = 0.f; ss[fn] = 0.f;
    }
#pragma unroll
    for (int fm = 0; fm < 4; ++fm) {
#pragma unroll
        for (int q = 0; q < 4; ++q) {
            int r = row0 + wm * 64 + fm * 16 + fc * 4 + q;
            if (r < M) {
#pragma unroll
                for (int fn = 0; fn < FN; ++fn) {
                    float h = acc[fm][fn][q] + bias[fn];
                    Hb[(size_t)r * NOUT + cw + fn * 16 + fr] = f2bf(h);
                    if constexpr (STATS) { s[fn] += h; ss[fn] += h * h; }
                }
            }
        }
    }
    if constexpr (STATS) {
#pragma unroll
        for (int fn = 0; fn < FN; ++fn) {
            float sv = s[fn], sq = ss[fn];
            sv += __shfl_xor(sv, 16); sv += __shfl_xor(sv, 32);
            sq += __shfl_xor(sq, 16); sq += __shfl_xor(sq, 32);
            if (fc == 0) {
                atomicAdd(&sums[cw + fn * 16 + fr], sv);
                atomicAdd(&sumsq[cw + fn * 16 + fr], sq);
            }
        }
    }
}

// ---------------- BN column stats (vectorized two-level) ----------------
template <int M>
__global__ __launch_bounds__(256) void col_stats_fast(const u16* __restrict__ H,
                                                      float* __restrict__ sums,
                                                      float* __restrict__ sumsq, int nrows) {
    constexpr int C4 = M / 8;
    constexpr int RPB = 256 / C4;
    __shared__ float ls[M], lss[M];
    for (int j = threadIdx.x; j < M; j += 256) { ls[j] = 0.f; lss[j] = 0.f; }
    __syncthreads();
    const int c = threadIdx.x % C4;
    const int rg = threadIdx.x / C4;
    float s[8] = {}, ss[8] = {};
    const uint4* H4 = (const uint4*)H;
    for (int r = blockIdx.x * RPB + rg; r < nrows; r += gridDim.x * RPB) {
        uint4 v = H4[(size_t)r * C4 + c];
        float x0, x1, x2, x3, x4, x5, x6, x7;
        bf2(v.x, x0, x1); bf2(v.y, x2, x3); bf2(v.z, x4, x5); bf2(v.w, x6, x7);
        s[0] += x0; ss[0] += x0 * x0;  s[1] += x1; ss[1] += x1 * x1;
        s[2] += x2; ss[2] += x2 * x2;  s[3] += x3; ss[3] += x3 * x3;
        s[4] += x4; ss[4] += x4 * x4;  s[5] += x5; ss[5] += x5 * x5;
        s[6] += x6; ss[6] += x6 * x6;  s[7] += x7; ss[7] += x7 * x7;
    }
#pragma unroll
    for (int j = 0; j < 8; ++j) {
        atomicAdd(&ls[c * 8 + j], s[j]);
        atomicAdd(&lss[c * 8 + j], ss[j]);
    }
    __syncthreads();
    for (int j = threadIdx.x; j < M; j += 256) {
        atomicAdd(&sums[j], ls[j]);
        atomicAdd(&sumsq[j], lss[j]);
    }
}

// ---------------- BN finalize ----------------
template <int M>
__global__ void bn_finalize(const float* __restrict__ sums, const float* __restrict__ sumsq,
                            const float* __restrict__ g, const float* __restrict__ beta,
                            float* __restrict__ scale, float* __restrict__ shift, int nrows) {
    int j = threadIdx.x;
    if (j >= M) return;
    float mean = sums[j] / nrows;
    float var = fmaxf(sumsq[j] / nrows - mean * mean, 0.f);
    float sc = g[j] * rsqrtf(var + BN_EPS);
    scale[j] = sc;
    shift[j] = beta[j] - mean * sc;
}

// ---------------- head with fused BN3+ReLU ----------------
__global__ __launch_bounds__(256) void head_bn(const u16* __restrict__ H3pre,
                                               const float* __restrict__ sc,
                                               const float* __restrict__ sh,
                                               const float* __restrict__ wh,
                                               const float* __restrict__ bh,
                                               float* __restrict__ out, int n) {
    int i = blockIdx.x * blockDim.x + threadIdx.x;
    if (i >= n) return;
    const uint4* h4 = (const uint4*)(H3pre + (size_t)i * 64);
    float acc = bh[0];
#pragma unroll
    for (int c = 0; c < 8; ++c) {
        uint4 v = h4[c];
        float x0, x1, x2, x3, x4, x5, x6, x7;
        bf2(v.x, x0, x1); bf2(v.y, x2, x3); bf2(v.z, x4, x5); bf2(v.w, x6, x7);
        const float* s = sc + c * 8;
        const float* t = sh + c * 8;
        const float* w = wh + c * 8;
        acc += fmaxf(fmaf(x0, s[0], t[0]), 0.f) * w[0];
        acc += fmaxf(fmaf(x1, s[1], t[1]), 0.f) * w[1];
        acc += fmaxf(fmaf(x2, s[2], t[2]), 0.f) * w[2];
        acc += fmaxf(fmaf(x3, s[3], t[3]), 0.f) * w[3];
        acc += fmaxf(fmaf(x4, s[4], t[4]), 0.f) * w[4];
        acc += fmaxf(fmaf(x5, s[5], t[5]), 0.f) * w[5];
        acc += fmaxf(fmaf(x6, s[6], t[6]), 0.f) * w[6];
        acc += fmaxf(fmaf(x7, s[7], t[7]), 0.f) * w[7];
    }
    out[i] = acc;
}

// ---------------- launch ----------------
extern "C" void kernel_launch(void* const* d_in, const int* in_sizes, int n_in,
                              void* d_out, int out_size, void* d_ws, size_t ws_size,
                              hipStream_t stream) {
    const int N = N_NODES, E = N_EDGES;
    const float* x   = (const float*)d_in[0];
    const int*   ei  = (const int*)d_in[1];
    const int*   src = ei;
    const int*   dst = ei + E;
    const float* w1l = (const float*)d_in[2];
    const float* b1l = (const float*)d_in[3];
    const float* w1r = (const float*)d_in[4];
    const float* g1  = (const float*)d_in[5];
    const float* be1 = (const float*)d_in[6];
    const float* w2l = (const float*)d_in[7];
    const float* b2l = (const float*)d_in[8];
    const float* w2r = (const float*)d_in[9];
    const float* g2  = (const float*)d_in[10];
    const float* be2 = (const float*)d_in[11];
    const float* w3l = (const float*)d_in[12];
    const float* b3l = (const float*)d_in[13];
    const float* w3r = (const float*)d_in[14];
    const float* g3  = (const float*)d_in[15];
    const float* be3 = (const float*)d_in[16];
    const float* wh  = (const float*)d_in[17];
    const float* bh  = (const float*)d_in[18];
    float* out = (float*)d_out;

    // ---- workspace layout ----
    char* base = (char*)d_ws;
    size_t off = 0;
    auto alloc = [&](size_t bytes) -> void* {
        void* r = base + off;
        off += (bytes + 255) & ~(size_t)255;
        return r;
    };
    const int NB = (N + 255) / 256;  // 196
    int*   rowptr = (int*)alloc((N + 8) * sizeof(int));
    int*   csr    = (int*)alloc((size_t)E * sizeof(int));
    int*   deg_i  = (int*)alloc(N * sizeof(int));
    int*   cursor = (int*)alloc(N * sizeof(int));
    int*   bsum   = (int*)alloc(256 * sizeof(int));
    float* inv    = (float*)alloc(N * sizeof(float));
    u16*   xb     = (u16*)alloc((size_t)NP * 256 * 2);
    u16*   sB     = (u16*)alloc((size_t)NP * 256 * 2);
    u16*   hpre1  = (u16*)alloc((size_t)NP * 256 * 2);
    u16*   hpre2  = (u16*)alloc((size_t)NP * 256 * 2);   // [P|Q] layer 2
    u16*   h2pre  = (u16*)alloc((size_t)NP * 128 * 2);
    u16*   hpre3  = (u16*)alloc((size_t)NP * 128 * 2);   // [P|Q] layer 3
    u16*   h3pre  = (u16*)alloc((size_t)NP * 64 * 2);
    u16*   wt1    = (u16*)alloc((size_t)131072 * 2);
    u16*   wt2    = (u16*)alloc((size_t)65536 * 2);
    u16*   wt3    = (u16*)alloc((size_t)16384 * 2);
    // stats: zeroed prefix [sums1 256][sumsq1 256][sums2 128][sumsq2 128]
    //        [sums3 64][sumsq3 64] = 896; then scale/shift (896)
    const int ZFLOATS = 896;
    float* stats  = (float*)alloc((ZFLOATS + 896) * sizeof(float));
    float* sums1 = stats,       *sumsq1 = stats + 256;
    float* sums2 = stats + 512, *sumsq2 = stats + 640;
    float* sums3 = stats + 768, *sumsq3 = stats + 832;
    float* post   = stats + ZFLOATS;
    float* scale1 = post,       *shift1 = post + 256;
    float* scale2 = post + 512, *shift2 = post + 640;
    float* scale3 = post + 768, *shift3 = post + 832;
    float* bias2  = (float*)alloc(256 * sizeof(float));
    float* bias3  = (float*)alloc(128 * sizeof(float));

    const int MB = NP / 128;  // 391

    // prologue: convert x, zero deg+stats, build weights/biases
    prologue<<<2048, 256, 0, stream>>>(x, xb, N * 256 / 8, deg_i, N / 4,
                                       stats, ZFLOATS / 4,
                                       w1l, w1r, w2l, w2r, w3l, w3r, b2l, b3l,
                                       wt1, wt2, wt3, bias2, bias3);

    // CSR build
    deg_count<<<(E + 255) / 256, 256, 0, stream>>>(dst, deg_i, E);
    scan_phase1<<<NB, 256, 0, stream>>>(deg_i, rowptr, bsum, N);
    scan_phase2<<<1, 256, 0, stream>>>(bsum, rowptr, NB, N);
    scan_phase3<<<NB, 256, 0, stream>>>(rowptr, bsum, deg_i, inv, cursor, N);
    csr_fill<<<(E + 255) / 256, 256, 0, stream>>>(src, dst, rowptr, cursor, csr, E);

    // layer 1: agg-first, [S|X] K=512 -> 256, stats fused in GEMM epilogue
    gather_mean_bf16<256><<<(N * 32 + 255) / 256, 256, 0, stream>>>(xb, rowptr, csr, inv, sB, N);
    sage_gemm<256, 512, 256, true, false><<<MB, 256, 0, stream>>>(
        sB, xb, wt1, b1l, nullptr, nullptr, hpre1, sums1, sumsq1, N);
    bn_finalize<256><<<1, 256, 0, stream>>>(sums1, sumsq1, g1, be1, scale1, shift1, N);

    // layer 2: transform-first, BN1+ReLU fused into A staging
    sage_gemm<256, 256, 256, false, true><<<MB, 256, 0, stream>>>(
        hpre1, hpre1, wt2, bias2, scale1, shift1, hpre2, nullptr, nullptr, N);
    gather_add_bf16<128><<<(N * 16 + 255) / 256, 256, 0, stream>>>(hpre2, rowptr, csr, inv, h2pre, N);
    col_stats_fast<128><<<256, 256, 0, stream>>>(h2pre, sums2, sumsq2, N);
    bn_finalize<128><<<1, 128, 0, stream>>>(sums2, sumsq2, g2, be2, scale2, shift2, N);

    // layer 3: transform-first, BN2+ReLU fused into A staging
    sage_gemm<128, 128, 128, false, true><<<MB, 256, 0, stream>>>(
        h2pre, h2pre, wt3, bias3, scale2, shift2, hpre3, nullptr, nullptr, N);
    gather_add_bf16<64><<<(N * 8 + 255) / 256, 256, 0, stream>>>(hpre3, rowptr, csr, inv, h3pre, N);
    col_stats_fast<64><<<256, 256, 0, stream>>>(h3pre, sums3, sumsq3, N);
    bn_finalize<64><<<1, 64, 0, stream>>>(sums3, sumsq3, g3, be3, scale3, shift3, N);

    // head with fused BN3+ReLU
    head_bn<<<(N + 255) / 256, 256, 0, stream>>>(h3pre, scale3, shift3, wh, bh, out, N);
}

// Round 14
// 268.370 us; speedup vs baseline: 2.7716x; 1.1237x over previous
//
#include <hip/hip_runtime.h>
#include <cstddef>
#include <cstdint>

#define N_NODES 50000
#define N_EDGES 800000
#define NP 50048   // 391 * 128, padded row count
static constexpr float BN_EPS = 1e-5f;
static constexpr int NREP = 32;  // replicated stat accumulators (contention spread)

typedef unsigned short u16;
typedef short bf16x8 __attribute__((ext_vector_type(8)));
typedef float f32x4 __attribute__((ext_vector_type(4)));

// ---------------- helpers ----------------
__device__ inline u16 f2bf(float f) {
    union { float f; unsigned u; } v; v.f = f;
    unsigned r = v.u + 0x7fffu + ((v.u >> 16) & 1u);
    return (u16)(r >> 16);
}
__device__ inline unsigned pack2(float a, float b) {
    return (unsigned)f2bf(a) | ((unsigned)f2bf(b) << 16);
}
__device__ inline void addbf2(unsigned u, float& lo, float& hi) {
    union { unsigned u; float f; } t;
    t.u = u << 16; lo += t.f;
    t.u = u & 0xFFFF0000u; hi += t.f;
}
__device__ inline void bf2(unsigned u, float& lo, float& hi) {
    union { unsigned u; float f; } t;
    t.u = u << 16; lo = t.f;
    t.u = u & 0xFFFF0000u; hi = t.f;
}
__device__ inline uint4 bnrelu_pack(uint4 v, float4 sc0, float4 sc1, float4 sh0, float4 sh1) {
    float x0, x1, x2, x3, x4, x5, x6, x7;
    bf2(v.x, x0, x1); bf2(v.y, x2, x3); bf2(v.z, x4, x5); bf2(v.w, x6, x7);
    x0 = fmaxf(fmaf(x0, sc0.x, sh0.x), 0.f); x1 = fmaxf(fmaf(x1, sc0.y, sh0.y), 0.f);
    x2 = fmaxf(fmaf(x2, sc0.z, sh0.z), 0.f); x3 = fmaxf(fmaf(x3, sc0.w, sh0.w), 0.f);
    x4 = fmaxf(fmaf(x4, sc1.x, sh1.x), 0.f); x5 = fmaxf(fmaf(x5, sc1.y, sh1.y), 0.f);
    x6 = fmaxf(fmaf(x6, sc1.z, sh1.z), 0.f); x7 = fmaxf(fmaf(x7, sc1.w, sh1.w), 0.f);
    uint4 u;
    u.x = pack2(x0, x1); u.y = pack2(x2, x3);
    u.z = pack2(x4, x5); u.w = pack2(x6, x7);
    return u;
}

// ---------------- prologue: convert x, zero deg+stats, build weights/biases ----------------
__global__ __launch_bounds__(256) void prologue(const float* __restrict__ in,
                                                u16* __restrict__ out, int n8,
                                                int* __restrict__ dz, int ndz4,
                                                float* __restrict__ sz, int nsz4,
                                                const float* __restrict__ w1l, const float* __restrict__ w1r,
                                                const float* __restrict__ w2l, const float* __restrict__ w2r,
                                                const float* __restrict__ w3l, const float* __restrict__ w3r,
                                                const float* __restrict__ b2l, const float* __restrict__ b3l,
                                                u16* __restrict__ wt1, u16* __restrict__ wt2,
                                                u16* __restrict__ wt3,
                                                float* __restrict__ bias2, float* __restrict__ bias3) {
    const int tid = blockIdx.x * 256 + threadIdx.x;
    const int stride = gridDim.x * 256;
    int4* d4 = (int4*)dz;
    for (int i = tid; i < ndz4; i += stride) d4[i] = make_int4(0, 0, 0, 0);
    float4* z4 = (float4*)sz;
    for (int i = tid; i < nsz4; i += stride) z4[i] = make_float4(0.f, 0.f, 0.f, 0.f);
    const float4* in4 = (const float4*)in;
    uint4* out4 = (uint4*)out;
    for (int i = tid; i < n8; i += stride) {
        float4 a = in4[2 * i], b = in4[2 * i + 1];
        uint4 u;
        u.x = pack2(a.x, a.y); u.y = pack2(a.z, a.w);
        u.z = pack2(b.x, b.y); u.w = pack2(b.z, b.w);
        out4[i] = u;
    }
    for (int i = tid; i < 213376; i += stride) {
        int idx = i;
        if (idx < 131072) {  // wt1[n][k]: K=512 concat-K
            int n = idx >> 9, k = idx & 511;
            float v = (k < 256) ? w1l[(size_t)k * 256 + n] : w1r[(size_t)(k - 256) * 256 + n];
            wt1[idx] = f2bf(v); continue;
        }
        idx -= 131072;
        if (idx < 65536) {   // wt2[n][k]: concat-N, D=128
            int n = idx >> 8, k = idx & 255;
            float v = (n < 128) ? w2l[(size_t)k * 128 + n] : w2r[(size_t)k * 128 + (n - 128)];
            wt2[idx] = f2bf(v); continue;
        }
        idx -= 65536;
        if (idx < 16384) {   // wt3[n][k]: concat-N, D=64
            int n = idx >> 7, k = idx & 127;
            float v = (n < 64) ? w3l[(size_t)k * 64 + n] : w3r[(size_t)k * 64 + (n - 64)];
            wt3[idx] = f2bf(v); continue;
        }
        idx -= 16384;
        if (idx < 256) { bias2[idx] = (idx < 128) ? 0.f : b2l[idx - 128]; continue; }
        idx -= 256;
        if (idx < 128) { bias3[idx] = (idx < 64) ? 0.f : b3l[idx - 64]; continue; }
    }
}

// ---------------- CSR build ----------------
__global__ void deg_count(const int* __restrict__ dst, int* __restrict__ deg, int E) {
    int i = blockIdx.x * blockDim.x + threadIdx.x;
    if (i < E) atomicAdd(&deg[dst[i]], 1);
}

__global__ __launch_bounds__(256) void scan_phase1(const int* __restrict__ deg,
                                                   int* __restrict__ rowptr,
                                                   int* __restrict__ blocksum, int n) {
    __shared__ int s[256];
    const int t = threadIdx.x;
    const int i = blockIdx.x * 256 + t;
    int d = (i < n) ? deg[i] : 0;
    s[t] = d;
    __syncthreads();
    for (int off = 1; off < 256; off <<= 1) {
        int v = (t >= off) ? s[t - off] : 0;
        __syncthreads();
        s[t] += v;
        __syncthreads();
    }
    if (i < n) rowptr[i] = s[t] - d;
    if (t == 255) blocksum[blockIdx.x] = s[t];
}

__global__ __launch_bounds__(256) void scan_phase2(int* __restrict__ blocksum,
                                                   int* __restrict__ rowptr, int nb, int n) {
    __shared__ int s[256];
    const int t = threadIdx.x;
    int d = (t < nb) ? blocksum[t] : 0;
    s[t] = d;
    __syncthreads();
    for (int off = 1; off < 256; off <<= 1) {
        int v = (t >= off) ? s[t - off] : 0;
        __syncthreads();
        s[t] += v;
        __syncthreads();
    }
    if (t < nb) blocksum[t] = s[t] - d;
    if (t == 255) rowptr[n] = s[t];
}

// also zeroes cursor
__global__ __launch_bounds__(256) void scan_phase3(int* __restrict__ rowptr,
                                                   const int* __restrict__ blocksum,
                                                   const int* __restrict__ deg,
                                                   float* __restrict__ inv,
                                                   int* __restrict__ cursor, int n) {
    int i = blockIdx.x * 256 + threadIdx.x;
    if (i >= n) return;
    rowptr[i] += blocksum[i >> 8];
    inv[i] = 1.0f / fmaxf((float)deg[i], 1.0f);
    cursor[i] = 0;
}

__global__ void csr_fill(const int* __restrict__ src, const int* __restrict__ dst,
                         const int* __restrict__ rowptr, int* __restrict__ cursor,
                         int* __restrict__ csr, int E) {
    int e = blockIdx.x * blockDim.x + threadIdx.x;
    if (e >= E) return;
    int d = dst[e];
    int p = atomicAdd(&cursor[d], 1);
    csr[rowptr[d] + p] = src[e];
}

// ---------------- gather-mean (layer 1): index-prefetch pipeline ----------------
template <int KH>
__global__ __launch_bounds__(256) void gather_mean_bf16(const u16* __restrict__ F,
                                                        const int* __restrict__ rowptr,
                                                        const int* __restrict__ csr,
                                                        const float* __restrict__ inv,
                                                        u16* __restrict__ Sout, int N) {
    constexpr int CG = KH / 8;
    constexpr int NPB = 256 / CG;
    const int c = threadIdx.x % CG;
    const int node = blockIdx.x * NPB + threadIdx.x / CG;
    if (node >= N) return;
    const uint4* F4 = (const uint4*)F;
    float a0 = 0, a1 = 0, a2 = 0, a3 = 0, a4 = 0, a5 = 0, a6 = 0, a7 = 0;
    const int beg = rowptr[node], end = rowptr[node + 1];
    int k = beg;
    if (end - beg >= 4) {
        int i0 = csr[k], i1 = csr[k + 1], i2 = csr[k + 2], i3 = csr[k + 3];
        k += 4;
        for (; k + 3 < end; k += 4) {
            uint4 v0 = F4[(size_t)i0 * CG + c];
            uint4 v1 = F4[(size_t)i1 * CG + c];
            uint4 v2 = F4[(size_t)i2 * CG + c];
            uint4 v3 = F4[(size_t)i3 * CG + c];
            i0 = csr[k]; i1 = csr[k + 1]; i2 = csr[k + 2]; i3 = csr[k + 3];
            addbf2(v0.x, a0, a1); addbf2(v0.y, a2, a3); addbf2(v0.z, a4, a5); addbf2(v0.w, a6, a7);
            addbf2(v1.x, a0, a1); addbf2(v1.y, a2, a3); addbf2(v1.z, a4, a5); addbf2(v1.w, a6, a7);
            addbf2(v2.x, a0, a1); addbf2(v2.y, a2, a3); addbf2(v2.z, a4, a5); addbf2(v2.w, a6, a7);
            addbf2(v3.x, a0, a1); addbf2(v3.y, a2, a3); addbf2(v3.z, a4, a5); addbf2(v3.w, a6, a7);
        }
        uint4 v0 = F4[(size_t)i0 * CG + c];
        uint4 v1 = F4[(size_t)i1 * CG + c];
        uint4 v2 = F4[(size_t)i2 * CG + c];
        uint4 v3 = F4[(size_t)i3 * CG + c];
        addbf2(v0.x, a0, a1); addbf2(v0.y, a2, a3); addbf2(v0.z, a4, a5); addbf2(v0.w, a6, a7);
        addbf2(v1.x, a0, a1); addbf2(v1.y, a2, a3); addbf2(v1.z, a4, a5); addbf2(v1.w, a6, a7);
        addbf2(v2.x, a0, a1); addbf2(v2.y, a2, a3); addbf2(v2.z, a4, a5); addbf2(v2.w, a6, a7);
        addbf2(v3.x, a0, a1); addbf2(v3.y, a2, a3); addbf2(v3.z, a4, a5); addbf2(v3.w, a6, a7);
    }
    for (; k < end; ++k) {
        uint4 v0 = F4[(size_t)csr[k] * CG + c];
        addbf2(v0.x, a0, a1); addbf2(v0.y, a2, a3); addbf2(v0.z, a4, a5); addbf2(v0.w, a6, a7);
    }
    const float w = inv[node];
    uint4 u;
    u.x = pack2(a0 * w, a1 * w); u.y = pack2(a2 * w, a3 * w);
    u.z = pack2(a4 * w, a5 * w); u.w = pack2(a6 * w, a7 * w);
    ((uint4*)Sout)[(size_t)node * CG + c] = u;
}

// ---------------- gather-add + fused BN stats (shfl-reduce, replicated accum, NO fence) ----------------
template <int D>
__global__ __launch_bounds__(256) void gather_add_stats(const u16* __restrict__ PQ,
                                                        const int* __restrict__ rowptr,
                                                        const int* __restrict__ csr,
                                                        const float* __restrict__ inv,
                                                        u16* __restrict__ Hpre,
                                                        float* __restrict__ repS,
                                                        float* __restrict__ repQ, int N) {
    constexpr int CG = D / 8;
    constexpr int NPB = 256 / CG;
    constexpr int RS4 = D / 4;
    const int t = threadIdx.x;
    const int c = t % CG;
    const int node = blockIdx.x * NPB + t / CG;
    float y[8] = {};
    if (node < N) {
        const uint4* PQ4 = (const uint4*)PQ;
        float a0 = 0, a1 = 0, a2 = 0, a3 = 0, a4 = 0, a5 = 0, a6 = 0, a7 = 0;
        const int beg = rowptr[node], end = rowptr[node + 1];
        int k = beg;
        if (end - beg >= 4) {
            int i0 = csr[k], i1 = csr[k + 1], i2 = csr[k + 2], i3 = csr[k + 3];
            k += 4;
            for (; k + 3 < end; k += 4) {
                uint4 v0 = PQ4[(size_t)i0 * RS4 + c];
                uint4 v1 = PQ4[(size_t)i1 * RS4 + c];
                uint4 v2 = PQ4[(size_t)i2 * RS4 + c];
                uint4 v3 = PQ4[(size_t)i3 * RS4 + c];
                i0 = csr[k]; i1 = csr[k + 1]; i2 = csr[k + 2]; i3 = csr[k + 3];
                addbf2(v0.x, a0, a1); addbf2(v0.y, a2, a3); addbf2(v0.z, a4, a5); addbf2(v0.w, a6, a7);
                addbf2(v1.x, a0, a1); addbf2(v1.y, a2, a3); addbf2(v1.z, a4, a5); addbf2(v1.w, a6, a7);
                addbf2(v2.x, a0, a1); addbf2(v2.y, a2, a3); addbf2(v2.z, a4, a5); addbf2(v2.w, a6, a7);
                addbf2(v3.x, a0, a1); addbf2(v3.y, a2, a3); addbf2(v3.z, a4, a5); addbf2(v3.w, a6, a7);
            }
            uint4 v0 = PQ4[(size_t)i0 * RS4 + c];
            uint4 v1 = PQ4[(size_t)i1 * RS4 + c];
            uint4 v2 = PQ4[(size_t)i2 * RS4 + c];
            uint4 v3 = PQ4[(size_t)i3 * RS4 + c];
            addbf2(v0.x, a0, a1); addbf2(v0.y, a2, a3); addbf2(v0.z, a4, a5); addbf2(v0.w, a6, a7);
            addbf2(v1.x, a0, a1); addbf2(v1.y, a2, a3); addbf2(v1.z, a4, a5); addbf2(v1.w, a6, a7);
            addbf2(v2.x, a0, a1); addbf2(v2.y, a2, a3); addbf2(v2.z, a4, a5); addbf2(v2.w, a6, a7);
            addbf2(v3.x, a0, a1); addbf2(v3.y, a2, a3); addbf2(v3.z, a4, a5); addbf2(v3.w, a6, a7);
        }
        for (; k < end; ++k) {
            uint4 v0 = PQ4[(size_t)csr[k] * RS4 + c];
            addbf2(v0.x, a0, a1); addbf2(v0.y, a2, a3); addbf2(v0.z, a4, a5); addbf2(v0.w, a6, a7);
        }
        const float w = inv[node];
        uint4 q = PQ4[(size_t)node * RS4 + D / 8 + c];
        float q0, q1, q2, q3, q4, q5, q6, q7;
        bf2(q.x, q0, q1); bf2(q.y, q2, q3); bf2(q.z, q4, q5); bf2(q.w, q6, q7);
        uint4 u;
        u.x = pack2(a0 * w + q0, a1 * w + q1);
        u.y = pack2(a2 * w + q2, a3 * w + q3);
        u.z = pack2(a4 * w + q4, a5 * w + q5);
        u.w = pack2(a6 * w + q6, a7 * w + q7);
        ((uint4*)Hpre)[(size_t)node * (D / 8) + c] = u;
        // stats on the bf16-rounded values
        bf2(u.x, y[0], y[1]); bf2(u.y, y[2], y[3]);
        bf2(u.z, y[4], y[5]); bf2(u.w, y[6], y[7]);
    }
    // shfl-butterfly over node-groups within the wave (lanes with equal c combine)
    float sq[8];
#pragma unroll
    for (int j = 0; j < 8; ++j) sq[j] = y[j] * y[j];
#pragma unroll
    for (int off = CG; off < 64; off <<= 1) {
#pragma unroll
        for (int j = 0; j < 8; ++j) {
            y[j] += __shfl_xor(y[j], off);
            sq[j] += __shfl_xor(sq[j], off);
        }
    }
    __shared__ float redS[4][D], redQ[4][D];
    const int w = t >> 6;
    if ((t & 63) < CG) {
#pragma unroll
        for (int j = 0; j < 8; ++j) {
            redS[w][c * 8 + j] = y[j];
            redQ[w][c * 8 + j] = sq[j];
        }
    }
    __syncthreads();
    const int rep = (blockIdx.x & (NREP - 1)) * D;
    if (t < D) {
        float s = redS[0][t] + redS[1][t] + redS[2][t] + redS[3][t];
        float ss = redQ[0][t] + redQ[1][t] + redQ[2][t] + redQ[3][t];
        atomicAdd(&repS[rep + t], s);
        atomicAdd(&repQ[rep + t], ss);
    }
}

// ---------------- MFMA GEMM ----------------
// STATS: fused column sums/sumsq (shfl + atomics) for layer-1 BN.
// BNA: A reg-staged with fused relu(a*sc+sh); scale/shift computed per-block in LDS
//      from sums/sumsq (NREPIN replicas) — removes bn_finalize dispatches.
template <int KH, int K, int NOUT, bool STATS, bool BNA, int NREPIN>
__global__ __launch_bounds__(256, 2) void sage_gemm(const u16* __restrict__ S,
                                                    const u16* __restrict__ X,
                                                    const u16* __restrict__ WT,
                                                    const float* __restrict__ BL,
                                                    const float* __restrict__ sumsIn,
                                                    const float* __restrict__ sumsqIn,
                                                    const float* __restrict__ gIn,
                                                    const float* __restrict__ betaIn,
                                                    u16* __restrict__ Hb,
                                                    float* __restrict__ sums,
                                                    float* __restrict__ sumsq, int M) {
    constexpr int NK = K / 32;
    constexpr int FN = NOUT / 32;
    constexpr int BUFSZ = 4096 + NOUT * 32;
    __shared__ __align__(16) u16 lds[2][BUFSZ];
    __shared__ float scLDS[BNA ? K : 1], shLDS[BNA ? K : 1];
    const int t = threadIdx.x;
    const int wid = t >> 6, lane = t & 63;
    const int row0 = blockIdx.x * 128;
    const int wm = wid >> 1, wn = wid & 1;
    const int fr = lane & 15, fc = lane >> 4;
    const int swz8 = (((lane & 3) ^ ((lane >> 3) & 3)) * 8);

    if constexpr (BNA) {
        for (int j = t; j < K; j += 256) {
            float s = 0.f, ss = 0.f;
#pragma unroll
            for (int r = 0; r < NREPIN; ++r) { s += sumsIn[r * K + j]; ss += sumsqIn[r * K + j]; }
            float mean = s / M;
            float var = fmaxf(ss / M - mean * mean, 0.f);
            float sc = gIn[j] * rsqrtf(var + BN_EPS);
            scLDS[j] = sc;
            shLDS[j] = betaIn[j] - mean * sc;
        }
        __syncthreads();
    }

    auto stageA_lds = [&](int buf, int ks) {
        const int k0 = ks * 32;
        const u16* srcA;
        int kb;
        if (k0 < KH) { srcA = S; kb = k0; } else { srcA = X; kb = k0 - KH; }
#pragma unroll
        for (int jj = 0; jj < 2; ++jj) {
            int j = wid + jj * 4;
            const u16* g = srcA + (size_t)(row0 + j * 16 + (lane >> 2)) * KH + kb + swz8;
            __builtin_amdgcn_global_load_lds(
                (const __attribute__((address_space(1))) void*)g,
                (__attribute__((address_space(3))) void*)&lds[buf][j * 512], 16, 0, 0);
        }
    };
    auto stageB = [&](int buf, int ks) {
        const int k0 = ks * 32;
#pragma unroll
        for (int jj = 0; jj < NOUT / 64; ++jj) {
            int j = wid * (NOUT / 64) + jj;
            const u16* gb = WT + (size_t)(j * 16 + (lane >> 2)) * K + k0 + swz8;
            __builtin_amdgcn_global_load_lds(
                (const __attribute__((address_space(1))) void*)gb,
                (__attribute__((address_space(3))) void*)&lds[buf][4096 + j * 512], 16, 0, 0);
        }
    };

    uint4 rA[2];
    auto loadA = [&](int ks) {
        const int k0 = ks * 32;
#pragma unroll
        for (int jj = 0; jj < 2; ++jj) {
            int j = wid + jj * 4;
            rA[jj] = *(const uint4*)(S + (size_t)(row0 + j * 16 + (lane >> 2)) * KH + k0 + swz8);
        }
    };
    auto writeA = [&](int buf, int ks) {
        const int k0 = ks * 32;
        float4 sc0 = *(const float4*)&scLDS[k0 + swz8];
        float4 sc1 = *(const float4*)&scLDS[k0 + swz8 + 4];
        float4 sh0 = *(const float4*)&shLDS[k0 + swz8];
        float4 sh1 = *(const float4*)&shLDS[k0 + swz8 + 4];
#pragma unroll
        for (int jj = 0; jj < 2; ++jj) {
            int j = wid + jj * 4;
            *(uint4*)&lds[buf][(size_t)j * 512 + lane * 8] = bnrelu_pack(rA[jj], sc0, sc1, sh0, sh1);
        }
    };

    f32x4 acc[4][FN] = {};

    auto compute = [&](int buf) {
        const u16* A = &lds[buf][0];
        const u16* B = &lds[buf][4096];
        const int swr = (fr >> 1) & 3;
        const int kc = (fc ^ swr) * 8;
        bf16x8 a[4], b[FN];
#pragma unroll
        for (int fm = 0; fm < 4; ++fm)
            a[fm] = *(const bf16x8*)&A[(wm * 64 + fm * 16 + fr) * 32 + kc];
#pragma unroll
        for (int fn = 0; fn < FN; ++fn)
            b[fn] = *(const bf16x8*)&B[(wn * (NOUT / 2) + fn * 16 + fr) * 32 + kc];
#pragma unroll
        for (int fm = 0; fm < 4; ++fm)
#pragma unroll
            for (int fn = 0; fn < FN; ++fn)
                acc[fm][fn] = __builtin_amdgcn_mfma_f32_16x16x32_bf16(a[fm], b[fn], acc[fm][fn], 0, 0, 0);
    };

    if constexpr (BNA) {
        static_assert(KH == K, "BNA requires single operand");
        loadA(0);
        writeA(0, 0);
        stageB(0, 0);
        if (NK > 1) loadA(1);
        for (int ks = 0; ks < NK; ++ks) {
            __syncthreads();
            if (ks + 1 < NK) {
                writeA((ks + 1) & 1, ks + 1);
                stageB((ks + 1) & 1, ks + 1);
                if (ks + 2 < NK) loadA(ks + 2);
            }
            compute(ks & 1);
        }
    } else {
        stageA_lds(0, 0);
        stageB(0, 0);
        for (int ks = 0; ks < NK; ++ks) {
            __syncthreads();
            if (ks + 1 < NK) {
                stageA_lds((ks + 1) & 1, ks + 1);
                stageB((ks + 1) & 1, ks + 1);
            }
            compute(ks & 1);
        }
    }

    const int cw = wn * (NOUT / 2);
    float bias[FN], s[FN], ss[FN];
#pragma unroll
    for (int fn = 0; fn < FN; ++fn) {
        bias[fn] = BL[cw + fn * 16 + fr];
        s[fn] = 0.f; ss[fn] = 0.f;
    }
#pragma unroll
    for (int fm = 0; fm < 4; ++fm) {
#pragma unroll
        for (int q = 0; q < 4; ++q) {
            int r = row0 + wm * 64 + fm * 16 + fc * 4 + q;
            if (r < M) {
#pragma unroll
                for (int fn = 0; fn < FN; ++fn) {
                    float h = acc[fm][fn][q] + bias[fn];
                    Hb[(size_t)r * NOUT + cw + fn * 16 + fr] = f2bf(h);
                    if constexpr (STATS) { s[fn] += h; ss[fn] += h * h; }
                }
            }
        }
    }
    if constexpr (STATS) {
#pragma unroll
        for (int fn = 0; fn < FN; ++fn) {
            float sv = s[fn], sq = ss[fn];
            sv += __shfl_xor(sv, 16); sv += __shfl_xor(sv, 32);
            sq += __shfl_xor(sq, 16); sq += __shfl_xor(sq, 32);
            if (fc == 0) {
                atomicAdd(&sums[cw + fn * 16 + fr], sv);
                atomicAdd(&sumsq[cw + fn * 16 + fr], sq);
            }
        }
    }
}

// ---------------- head: inline BN3 finalize (from replicas) + ReLU + dot ----------------
__global__ __launch_bounds__(256) void head_bn_fin(const u16* __restrict__ H3pre,
                                                   const float* __restrict__ repS,
                                                   const float* __restrict__ repQ,
                                                   const float* __restrict__ g,
                                                   const float* __restrict__ beta,
                                                   const float* __restrict__ wh,
                                                   const float* __restrict__ bh,
                                                   float* __restrict__ out, int n) {
    __shared__ float sc[64], sh[64];
    const int t = threadIdx.x;
    if (t < 64) {
        float s = 0.f, ss = 0.f;
#pragma unroll 8
        for (int r = 0; r < NREP; ++r) { s += repS[r * 64 + t]; ss += repQ[r * 64 + t]; }
        float mean = s / n;
        float var = fmaxf(ss / n - mean * mean, 0.f);
        float scv = g[t] * rsqrtf(var + BN_EPS);
        sc[t] = scv;
        sh[t] = beta[t] - mean * scv;
    }
    __syncthreads();
    int i = blockIdx.x * blockDim.x + t;
    if (i >= n) return;
    const uint4* h4 = (const uint4*)(H3pre + (size_t)i * 64);
    float acc = bh[0];
#pragma unroll
    for (int c = 0; c < 8; ++c) {
        uint4 v = h4[c];
        float x0, x1, x2, x3, x4, x5, x6, x7;
        bf2(v.x, x0, x1); bf2(v.y, x2, x3); bf2(v.z, x4, x5); bf2(v.w, x6, x7);
        const float* scp = sc + c * 8;
        const float* shp = sh + c * 8;
        const float* w = wh + c * 8;
        acc += fmaxf(fmaf(x0, scp[0], shp[0]), 0.f) * w[0];
        acc += fmaxf(fmaf(x1, scp[1], shp[1]), 0.f) * w[1];
        acc += fmaxf(fmaf(x2, scp[2], shp[2]), 0.f) * w[2];
        acc += fmaxf(fmaf(x3, scp[3], shp[3]), 0.f) * w[3];
        acc += fmaxf(fmaf(x4, scp[4], shp[4]), 0.f) * w[4];
        acc += fmaxf(fmaf(x5, scp[5], shp[5]), 0.f) * w[5];
        acc += fmaxf(fmaf(x6, scp[6], shp[6]), 0.f) * w[6];
        acc += fmaxf(fmaf(x7, scp[7], shp[7]), 0.f) * w[7];
    }
    out[i] = acc;
}

// ---------------- launch ----------------
extern "C" void kernel_launch(void* const* d_in, const int* in_sizes, int n_in,
                              void* d_out, int out_size, void* d_ws, size_t ws_size,
                              hipStream_t stream) {
    const int N = N_NODES, E = N_EDGES;
    const float* x   = (const float*)d_in[0];
    const int*   ei  = (const int*)d_in[1];
    const int*   src = ei;
    const int*   dst = ei + E;
    const float* w1l = (const float*)d_in[2];
    const float* b1l = (const float*)d_in[3];
    const float* w1r = (const float*)d_in[4];
    const float* g1  = (const float*)d_in[5];
    const float* be1 = (const float*)d_in[6];
    const float* w2l = (const float*)d_in[7];
    const float* b2l = (const float*)d_in[8];
    const float* w2r = (const float*)d_in[9];
    const float* g2  = (const float*)d_in[10];
    const float* be2 = (const float*)d_in[11];
    const float* w3l = (const float*)d_in[12];
    const float* b3l = (const float*)d_in[13];
    const float* w3r = (const float*)d_in[14];
    const float* g3  = (const float*)d_in[15];
    const float* be3 = (const float*)d_in[16];
    const float* wh  = (const float*)d_in[17];
    const float* bh  = (const float*)d_in[18];
    float* out = (float*)d_out;

    // ---- workspace layout ----
    char* base = (char*)d_ws;
    size_t off = 0;
    auto alloc = [&](size_t bytes) -> void* {
        void* r = base + off;
        off += (bytes + 255) & ~(size_t)255;
        return r;
    };
    const int NB = (N + 255) / 256;  // 196
    int*   rowptr = (int*)alloc((N + 8) * sizeof(int));
    int*   csr    = (int*)alloc((size_t)E * sizeof(int));
    int*   deg_i  = (int*)alloc(N * sizeof(int));
    int*   cursor = (int*)alloc(N * sizeof(int));
    int*   bsum   = (int*)alloc(256 * sizeof(int));
    float* inv    = (float*)alloc(N * sizeof(float));
    u16*   xb     = (u16*)alloc((size_t)NP * 256 * 2);
    u16*   sB     = (u16*)alloc((size_t)NP * 256 * 2);
    u16*   hpre1  = (u16*)alloc((size_t)NP * 256 * 2);
    u16*   hpre2  = (u16*)alloc((size_t)NP * 256 * 2);   // [P|Q] layer 2
    u16*   h2pre  = (u16*)alloc((size_t)NP * 128 * 2);
    u16*   hpre3  = (u16*)alloc((size_t)NP * 128 * 2);   // [P|Q] layer 3
    u16*   h3pre  = (u16*)alloc((size_t)NP * 64 * 2);
    u16*   wt1    = (u16*)alloc((size_t)131072 * 2);
    u16*   wt2    = (u16*)alloc((size_t)65536 * 2);
    u16*   wt3    = (u16*)alloc((size_t)16384 * 2);
    // stats (all zeroed by prologue): [sums1 256][sumsq1 256]
    //   [rep2S 32*128][rep2Q 32*128][rep3S 32*64][rep3Q 32*64]  = 12800 floats
    const int ZFLOATS = 512 + 2 * NREP * 128 + 2 * NREP * 64;
    float* stats  = (float*)alloc(ZFLOATS * sizeof(float));
    float* sums1 = stats,       *sumsq1 = stats + 256;
    float* rep2S = stats + 512,            *rep2Q = rep2S + NREP * 128;
    float* rep3S = rep2Q + NREP * 128,     *rep3Q = rep3S + NREP * 64;
    float* bias2  = (float*)alloc(256 * sizeof(float));
    float* bias3  = (float*)alloc(128 * sizeof(float));

    const int MB = NP / 128;  // 391

    // prologue: convert x, zero deg+stats, build weights/biases
    prologue<<<2048, 256, 0, stream>>>(x, xb, N * 256 / 8, deg_i, N / 4,
                                       stats, ZFLOATS / 4,
                                       w1l, w1r, w2l, w2r, w3l, w3r, b2l, b3l,
                                       wt1, wt2, wt3, bias2, bias3);

    // CSR build
    deg_count<<<(E + 255) / 256, 256, 0, stream>>>(dst, deg_i, E);
    scan_phase1<<<NB, 256, 0, stream>>>(deg_i, rowptr, bsum, N);
    scan_phase2<<<1, 256, 0, stream>>>(bsum, rowptr, NB, N);
    scan_phase3<<<NB, 256, 0, stream>>>(rowptr, bsum, deg_i, inv, cursor, N);
    csr_fill<<<(E + 255) / 256, 256, 0, stream>>>(src, dst, rowptr, cursor, csr, E);

    // layer 1: agg-first, [S|X] K=512 -> 256, stats fused in GEMM epilogue
    gather_mean_bf16<256><<<(N * 32 + 255) / 256, 256, 0, stream>>>(xb, rowptr, csr, inv, sB, N);
    sage_gemm<256, 512, 256, true, false, 1><<<MB, 256, 0, stream>>>(
        sB, xb, wt1, b1l, nullptr, nullptr, nullptr, nullptr, hpre1, sums1, sumsq1, N);

    // layer 2: transform-first; BN1 finalize computed per-block in GEMM (from sums1)
    sage_gemm<256, 256, 256, false, true, 1><<<MB, 256, 0, stream>>>(
        hpre1, hpre1, wt2, bias2, sums1, sumsq1, g1, be1, hpre2, nullptr, nullptr, N);
    gather_add_stats<128><<<(N * 16 + 255) / 256, 256, 0, stream>>>(
        hpre2, rowptr, csr, inv, h2pre, rep2S, rep2Q, N);

    // layer 3: transform-first; BN2 finalize computed per-block in GEMM (from rep2)
    sage_gemm<128, 128, 128, false, true, NREP><<<MB, 256, 0, stream>>>(
        h2pre, h2pre, wt3, bias3, rep2S, rep2Q, g2, be2, hpre3, nullptr, nullptr, N);
    gather_add_stats<64><<<(N * 8 + 255) / 256, 256, 0, stream>>>(
        hpre3, rowptr, csr, inv, h3pre, rep3S, rep3Q, N);

    // head: BN3 finalize inline (from rep3) + ReLU + dot
    head_bn_fin<<<(N + 255) / 256, 256, 0, stream>>>(h3pre, rep3S, rep3Q, g3, be3, wh, bh, out, N);
}